// Round 1
// baseline (1123.862 us; speedup 1.0000x reference)
//
#include <hip/hip_runtime.h>

#define Hh   256
#define NCn  20000
#define N1n  60000
#define N2n  60000
#define En   200000
#define Bn   512
#define OUTn 128

using bf16x8 = __attribute__((ext_vector_type(8))) __bf16;
using f32x4  = __attribute__((ext_vector_type(4))) float;

__device__ __forceinline__ float bf2f(unsigned short u) {
    union { unsigned int i; float f; } v; v.i = ((unsigned int)u) << 16; return v.f;
}
__device__ __forceinline__ unsigned short f2bf(float f) {
    union { float f; unsigned int i; } v; v.f = f;
    unsigned int r = v.i + 0x7FFFu + ((v.i >> 16) & 1u);
    return (unsigned short)(r >> 16);
}

// ---------------- input projection: out_bf16[M][256] = X[M][K] @ W[K][256] + b ----------
template<int K>
__global__ void proj_kernel(const float* __restrict__ X, const float* __restrict__ W,
                            const float* __restrict__ b, unsigned short* __restrict__ out) {
    __shared__ float xs[K];
    int m = blockIdx.x;
    int n = threadIdx.x;
    if (threadIdx.x < K) xs[threadIdx.x] = X[(size_t)m * K + threadIdx.x];
    __syncthreads();
    float acc = b[n];
#pragma unroll
    for (int k = 0; k < K; ++k) acc = fmaf(xs[k], W[k * Hh + n], acc);
    out[(size_t)m * Hh + n] = f2bf(acc);
}

// ---------------- weight prep: Wt[n][k] = W[k][n] * scale (bf16) ------------------------
__global__ void wt_prep(const float* __restrict__ W, float scale, unsigned short* __restrict__ Wt) {
    int idx = blockIdx.x * 256 + threadIdx.x;          // 65536
    int n = idx >> 8, k = idx & 255;
    Wt[idx] = f2bf(W[k * Hh + n] * scale);
}

// central concatenated weight: K=768 = [0.5*Wm1 ; 0.5*Wm3 ; 0.5*(Wr1+Wr3)], transposed
__global__ void wt_cat_prep(const float* __restrict__ Wm1, const float* __restrict__ Wm3,
                            const float* __restrict__ Wr1, const float* __restrict__ Wr3,
                            unsigned short* __restrict__ Wt) {
    int idx = blockIdx.x * 256 + threadIdx.x;          // 256*768
    int n = idx / 768, k = idx - n * 768;
    float v;
    if (k < 256)      v = 0.5f * Wm1[k * Hh + n];
    else if (k < 512) v = 0.5f * Wm3[(k - 256) * Hh + n];
    else              v = 0.5f * (Wr1[(k - 512) * Hh + n] + Wr3[(k - 512) * Hh + n]);
    Wt[idx] = f2bf(v);
}

__global__ void bias_central_prep(const float* __restrict__ b_msg, float* __restrict__ out) {
    int i = blockIdx.x * 256 + threadIdx.x;            // 512
    if (i >= 512) return;
    int l = i >> 8, n = i & 255;
    out[i] = 0.5f * (b_msg[(l * 4 + 1) * Hh + n] + b_msg[(l * 4 + 3) * Hh + n]);
}

// ---------------- CSR build ------------------------------------------------------------
__global__ void zero_i32(int* p, int n) {
    int i = blockIdx.x * 256 + threadIdx.x; if (i < n) p[i] = 0;
}
__global__ void deg_count(const int* __restrict__ dst, int* deg, int e) {
    int i = blockIdx.x * 256 + threadIdx.x; if (i < e) atomicAdd(&deg[dst[i]], 1);
}
__global__ void __launch_bounds__(1024) scan_chunk(const int* __restrict__ deg, int n,
                                                   int* __restrict__ rowptr, int* __restrict__ partials) {
    __shared__ int sh[1024];
    int tid = threadIdx.x;
    int i = blockIdx.x * 1024 + tid;
    int v = (i < n) ? deg[i] : 0;
    sh[tid] = v; __syncthreads();
    for (int off = 1; off < 1024; off <<= 1) {
        int t = (tid >= off) ? sh[tid - off] : 0; __syncthreads();
        sh[tid] += t; __syncthreads();
    }
    if (i < n) rowptr[i] = sh[tid] - v;       // exclusive within chunk
    if (tid == 1023) partials[blockIdx.x] = sh[1023];
}
__global__ void scan_partials(int* partials, int nchunks) {   // 1 block, 64 threads
    __shared__ int sh[64];
    int tid = threadIdx.x;
    int v = (tid < nchunks) ? partials[tid] : 0;
    sh[tid] = v; __syncthreads();
    for (int off = 1; off < 64; off <<= 1) {
        int t = (tid >= off) ? sh[tid - off] : 0; __syncthreads();
        sh[tid] += t; __syncthreads();
    }
    if (tid < nchunks) partials[tid] = sh[tid] - v;           // exclusive
}
__global__ void __launch_bounds__(1024) scan_add(int* rowptr, const int* __restrict__ partials,
                                                 int n, int e_total) {
    int i = blockIdx.x * 1024 + threadIdx.x;
    if (i < n) rowptr[i] += partials[blockIdx.x];
    if (blockIdx.x == 0 && threadIdx.x == 0) rowptr[n] = e_total;
}
__global__ void scatter_edges(const int* __restrict__ src, const int* __restrict__ dst,
                              const int* __restrict__ rowptr, int* fill, int* colsrc, int e) {
    int i = blockIdx.x * 256 + threadIdx.x;
    if (i < e) {
        int d = dst[i];
        int pos = rowptr[d] + atomicAdd(&fill[d], 1);
        colsrc[pos] = src[i];
    }
}

// ---------------- gather-based segment mean: one wave per dst node ---------------------
__global__ void agg_mean(const unsigned short* __restrict__ feat,
                         const int* __restrict__ rowptr, const int* __restrict__ colsrc,
                         unsigned short* __restrict__ out, int ostride, int ocol, int n_dst) {
    int gw = (blockIdx.x * blockDim.x + threadIdx.x) >> 6;
    int lane = threadIdx.x & 63;
    if (gw >= n_dst) return;
    int s = rowptr[gw], e = rowptr[gw + 1];
    float a0 = 0.f, a1 = 0.f, a2 = 0.f, a3 = 0.f;
    for (int i = s; i < e; ++i) {
        int sc = colsrc[i];
        ushort4 v = *reinterpret_cast<const ushort4*>(feat + (size_t)sc * Hh + lane * 4);
        a0 += bf2f(v.x); a1 += bf2f(v.y); a2 += bf2f(v.z); a3 += bf2f(v.w);
    }
    int c = e - s;
    float inv = 1.0f / (float)(c > 1 ? c : 1);
    ushort4 o;
    o.x = f2bf(a0 * inv); o.y = f2bf(a1 * inv); o.z = f2bf(a2 * inv); o.w = f2bf(a3 * inv);
    *reinterpret_cast<ushort4*>(out + (size_t)gw * ostride + ocol + lane * 4) = o;
}

// copy current central features into cat[:, 512:768]
__global__ void copy_to_cat(const unsigned short* __restrict__ hc, unsigned short* __restrict__ cat) {
    int idx = blockIdx.x * 256 + threadIdx.x;   // NC*32 threads, 8 elems each
    int m = idx >> 5, c = (idx & 31) * 8;
    *reinterpret_cast<uint4*>(cat + (size_t)m * 768 + 512 + c) =
        *reinterpret_cast<const uint4*>(hc + (size_t)m * Hh + c);
}

// ---------------- main GEMM: C[M][256] = A[M][K] @ W (Wt[n][k] transposed bf16) --------
// + bias + Add + optional relu. BM=64, 4 waves x 64 cols, BK=64 LDS-staged with XOR swizzle.
template<bool RELU>
__global__ void __launch_bounds__(256) gemm_n256(const unsigned short* __restrict__ A, int lda, int K,
                                                 const unsigned short* __restrict__ Wt,
                                                 const float* __restrict__ bias,
                                                 const unsigned short* __restrict__ Add,
                                                 unsigned short* __restrict__ C, int M) {
    __shared__ unsigned short As[64 * 64];
    const int tid = threadIdx.x;
    const int wid = tid >> 6, lane = tid & 63;
    const int lhi = lane >> 4, llo = lane & 15;
    const int m0 = blockIdx.x * 64;

    f32x4 acc[4][4];
#pragma unroll
    for (int r = 0; r < 4; ++r)
#pragma unroll
        for (int c = 0; c < 4; ++c) {
            acc[r][c][0] = 0.f; acc[r][c][1] = 0.f; acc[r][c][2] = 0.f; acc[r][c][3] = 0.f;
        }

    const int srow = tid >> 2;            // staging: row 0..63
    const int schunk = (tid & 3) * 2;     // chunk pair 0,2,4,6 (8 bf16 per chunk)
    const int grow = m0 + srow;
    const bool rowok = (grow < M);
    const unsigned short* gA = A + (size_t)grow * lda + schunk * 8;
    const int sw0 = srow * 64 + ((schunk ^ (srow & 7)) * 8);
    const int sw1 = srow * 64 + (((schunk + 1) ^ (srow & 7)) * 8);

    for (int kt = 0; kt < K; kt += 64) {
        __syncthreads();
        uint4 v0 = make_uint4(0, 0, 0, 0), v1 = make_uint4(0, 0, 0, 0);
        if (rowok) {
            v0 = *reinterpret_cast<const uint4*>(gA + kt);
            v1 = *reinterpret_cast<const uint4*>(gA + kt + 8);
        }
        *reinterpret_cast<uint4*>(&As[sw0]) = v0;
        *reinterpret_cast<uint4*>(&As[sw1]) = v1;
        __syncthreads();

#pragma unroll
        for (int kk = 0; kk < 2; ++kk) {
            bf16x8 af[4];
#pragma unroll
            for (int r = 0; r < 4; ++r) {
                int rl = r * 16 + llo;
                int ch = (kk * 4 + lhi) ^ (rl & 7);
                af[r] = *reinterpret_cast<const bf16x8*>(&As[rl * 64 + ch * 8]);
            }
            bf16x8 bfr[4];
#pragma unroll
            for (int c = 0; c < 4; ++c) {
                int n = wid * 64 + c * 16 + llo;
                bfr[c] = *reinterpret_cast<const bf16x8*>(Wt + (size_t)n * K + kt + kk * 32 + lhi * 8);
            }
#pragma unroll
            for (int r = 0; r < 4; ++r)
#pragma unroll
                for (int c = 0; c < 4; ++c)
                    acc[r][c] = __builtin_amdgcn_mfma_f32_16x16x32_bf16(af[r], bfr[c], acc[r][c], 0, 0, 0);
        }
    }

#pragma unroll
    for (int c = 0; c < 4; ++c) {
        int col = wid * 64 + c * 16 + llo;
        float bv = bias ? bias[col] : 0.0f;
#pragma unroll
        for (int r = 0; r < 4; ++r) {
            int rowb = m0 + r * 16 + lhi * 4;
#pragma unroll
            for (int j = 0; j < 4; ++j) {
                int rr = rowb + j;
                if (rr < M) {
                    float v = acc[r][c][j] + bv;
                    if (Add) v += bf2f(Add[(size_t)rr * Hh + col]);
                    if (RELU) v = fmaxf(v, 0.0f);
                    C[(size_t)rr * Hh + col] = f2bf(v);
                }
            }
        }
    }
}

// ---------------- pooling --------------------------------------------------------------
__global__ void graph_bounds(const int* __restrict__ batch, int n, int* __restrict__ bound) {
    int b = blockIdx.x * 256 + threadIdx.x;
    if (b > Bn) return;
    int lo = 0, hi = n;
    while (lo < hi) { int mid = (lo + hi) >> 1; if (batch[mid] < b) lo = mid + 1; else hi = mid; }
    bound[b] = lo;
}
__global__ void pool_mean(const unsigned short* __restrict__ feat, const int* __restrict__ bound,
                          float* __restrict__ outp) {
    int g = blockIdx.x, lane = threadIdx.x;   // 64 threads
    int s = bound[g], e = bound[g + 1];
    float a0 = 0.f, a1 = 0.f, a2 = 0.f, a3 = 0.f;
    for (int i = s; i < e; ++i) {
        ushort4 v = *reinterpret_cast<const ushort4*>(feat + (size_t)i * Hh + lane * 4);
        a0 += bf2f(v.x); a1 += bf2f(v.y); a2 += bf2f(v.z); a3 += bf2f(v.w);
    }
    int c = e - s;
    float inv = 1.0f / (float)(c > 1 ? c : 1);
    float* op = outp + (size_t)g * Hh + lane * 4;
    op[0] = a0 * inv; op[1] = a1 * inv; op[2] = a2 * inv; op[3] = a3 * inv;
}
__global__ void final_kernel(const float* __restrict__ p0, const float* __restrict__ p1,
                             const float* __restrict__ p2, const float* __restrict__ Wg,
                             const float* __restrict__ bg, float* __restrict__ out) {
    __shared__ float emb[Hh];
    int g = blockIdx.x, o = threadIdx.x;     // 128 threads
    for (int k = o; k < Hh; k += 128)
        emb[k] = (p0[g * Hh + k] + p1[g * Hh + k] + p2[g * Hh + k]) * (1.0f / 3.0f);
    __syncthreads();
    float acc = bg[o];
#pragma unroll 8
    for (int k = 0; k < Hh; ++k) acc = fmaf(emb[k], Wg[k * OUTn + o], acc);
    out[(size_t)g * OUTn + o] = acc;
}

// ---------------- host orchestration ----------------------------------------------------
extern "C" void kernel_launch(void* const* d_in, const int* in_sizes, int n_in,
                              void* d_out, int out_size, void* d_ws, size_t ws_size,
                              hipStream_t stream) {
    const float* x_central = (const float*)d_in[0];
    const float* x_cont    = (const float*)d_in[1];
    const float* x_categ   = (const float*)d_in[2];
    const int* ei_c2cont   = (const int*)d_in[3];
    const int* ei_cont2c   = (const int*)d_in[4];
    const int* ei_c2categ  = (const int*)d_in[5];
    const int* ei_categ2c  = (const int*)d_in[6];
    const int* batch_central = (const int*)d_in[7];
    const int* batch_cont    = (const int*)d_in[8];
    const int* batch_categ   = (const int*)d_in[9];
    const float* Wp_central = (const float*)d_in[11];
    const float* bp_central = (const float*)d_in[12];
    const float* Wp_cont    = (const float*)d_in[13];
    const float* bp_cont    = (const float*)d_in[14];
    const float* Wp_categ   = (const float*)d_in[15];
    const float* bp_categ   = (const float*)d_in[16];
    const float* W_msg  = (const float*)d_in[17];
    const float* b_msg  = (const float*)d_in[18];
    const float* W_root = (const float*)d_in[19];
    const float* Wg     = (const float*)d_in[20];
    const float* bg     = (const float*)d_in[21];
    float* out = (float*)d_out;

    char* base = (char*)d_ws;
    size_t off = 0;
    auto alloc = [&](size_t bytes) -> void* {
        off = (off + 255) & ~(size_t)255;
        void* p = base + off; off += bytes; return p;
    };

    unsigned short* hc   = (unsigned short*)alloc((size_t)NCn * Hh * 2);
    unsigned short* h1   = (unsigned short*)alloc((size_t)N1n * Hh * 2);
    unsigned short* h2   = (unsigned short*)alloc((size_t)N2n * Hh * 2);
    unsigned short* t0   = (unsigned short*)alloc((size_t)NCn * Hh * 2);
    unsigned short* t2   = (unsigned short*)alloc((size_t)NCn * Hh * 2);
    unsigned short* cat  = (unsigned short*)alloc((size_t)NCn * 768 * 2);
    unsigned short* agg0 = (unsigned short*)alloc((size_t)N1n * Hh * 2);
    unsigned short* agg2 = (unsigned short*)alloc((size_t)N2n * Hh * 2);

    unsigned short *Wt_msg0[2], *Wt_msg2[2], *Wt_root0[2], *Wt_root2[2], *Wt_cat[2];
    for (int l = 0; l < 2; ++l) {
        Wt_msg0[l]  = (unsigned short*)alloc(65536 * 2);
        Wt_msg2[l]  = (unsigned short*)alloc(65536 * 2);
        Wt_root0[l] = (unsigned short*)alloc(65536 * 2);
        Wt_root2[l] = (unsigned short*)alloc(65536 * 2);
        Wt_cat[l]   = (unsigned short*)alloc(768 * 256 * 2);
    }
    float* b_central = (float*)alloc(512 * 4);

    const int nd[4] = { N1n, NCn, N2n, NCn };
    const int* eis[4] = { ei_c2cont, ei_cont2c, ei_c2categ, ei_categ2c };
    int* rp[4]; int* cs[4];
    for (int r = 0; r < 4; ++r) {
        rp[r] = (int*)alloc((size_t)(nd[r] + 1) * 4);
        cs[r] = (int*)alloc((size_t)En * 4);
    }
    int* tmp      = (int*)alloc((size_t)60000 * 4);
    int* partials = (int*)alloc(64 * 4);
    float* pooled = (float*)alloc((size_t)3 * Bn * Hh * 4);
    int* bounds   = (int*)alloc((size_t)3 * (Bn + 1) * 4);
    (void)ws_size; (void)in_sizes; (void)n_in; (void)out_size;

    // --- weight prep ---
    for (int l = 0; l < 2; ++l) {
        const float* Wm = W_msg  + (size_t)l * 4 * 65536;
        const float* Wr = W_root + (size_t)l * 4 * 65536;
        wt_prep<<<256, 256, 0, stream>>>(Wm + 0 * 65536, 1.0f, Wt_msg0[l]);
        wt_prep<<<256, 256, 0, stream>>>(Wm + 2 * 65536, 1.0f, Wt_msg2[l]);
        wt_prep<<<256, 256, 0, stream>>>(Wr + 0 * 65536, 1.0f, Wt_root0[l]);
        wt_prep<<<256, 256, 0, stream>>>(Wr + 2 * 65536, 1.0f, Wt_root2[l]);
        wt_cat_prep<<<768, 256, 0, stream>>>(Wm + 1 * 65536, Wm + 3 * 65536,
                                             Wr + 1 * 65536, Wr + 3 * 65536, Wt_cat[l]);
    }
    bias_central_prep<<<2, 256, 0, stream>>>(b_msg, b_central);

    // --- input projections ---
    proj_kernel<64><<<NCn, 256, 0, stream>>>(x_central, Wp_central, bp_central, hc);
    proj_kernel<16><<<N1n, 256, 0, stream>>>(x_cont,    Wp_cont,    bp_cont,    h1);
    proj_kernel<16><<<N2n, 256, 0, stream>>>(x_categ,   Wp_categ,   bp_categ,   h2);

    // --- CSR build (shared by both layers) ---
    for (int r = 0; r < 4; ++r) {
        int n = nd[r];
        int nblk = (n + 255) / 256;
        int nch  = (n + 1023) / 1024;
        zero_i32<<<nblk, 256, 0, stream>>>(tmp, n);
        deg_count<<<(En + 255) / 256, 256, 0, stream>>>(eis[r] + En, tmp, En);
        scan_chunk<<<nch, 1024, 0, stream>>>(tmp, n, rp[r], partials);
        scan_partials<<<1, 64, 0, stream>>>(partials, nch);
        scan_add<<<nch, 1024, 0, stream>>>(rp[r], partials, n, En);
        zero_i32<<<nblk, 256, 0, stream>>>(tmp, n);
        scatter_edges<<<(En + 255) / 256, 256, 0, stream>>>(eis[r], eis[r] + En, rp[r], tmp, cs[r], En);
    }

    auto gemm = [&](const unsigned short* A, int lda, int K, const unsigned short* Wt,
                    const float* bias, const unsigned short* Add, unsigned short* C, int M, bool relu) {
        dim3 grid((M + 63) / 64), block(256);
        if (relu) gemm_n256<true><<<grid, block, 0, stream>>>(A, lda, K, Wt, bias, Add, C, M);
        else      gemm_n256<false><<<grid, block, 0, stream>>>(A, lda, K, Wt, bias, Add, C, M);
    };

    // --- GNN layers ---
    for (int l = 0; l < 2; ++l) {
        bool relu = (l == 0);
        // transform central on the small side for outgoing messages
        gemm(hc, Hh, Hh, Wt_msg0[l], nullptr, nullptr, t0, NCn, false);
        gemm(hc, Hh, Hh, Wt_msg2[l], nullptr, nullptr, t2, NCn, false);
        // aggregate children -> central into cat[:,0:256] and [:,256:512]
        agg_mean<<<(NCn * 64 + 255) / 256, 256, 0, stream>>>(h1, rp[1], cs[1], cat, 768, 0,   NCn);
        agg_mean<<<(NCn * 64 + 255) / 256, 256, 0, stream>>>(h2, rp[3], cs[3], cat, 768, 256, NCn);
        copy_to_cat<<<(NCn * 32) / 256, 256, 0, stream>>>(hc, cat);
        // aggregate transformed central -> children
        agg_mean<<<(N1n * 64 + 255) / 256, 256, 0, stream>>>(t0, rp[0], cs[0], agg0, 256, 0, N1n);
        agg_mean<<<(N2n * 64 + 255) / 256, 256, 0, stream>>>(t2, rp[2], cs[2], agg2, 256, 0, N2n);
        // updates (in-place safe: each block reads only its own rows)
        gemm(cat, 768, 768, Wt_cat[l], b_central + l * 256, nullptr, hc, NCn, relu);
        gemm(h1, Hh, Hh, Wt_root0[l], b_msg + (l * 4 + 0) * Hh, agg0, h1, N1n, relu);
        gemm(h2, Hh, Hh, Wt_root2[l], b_msg + (l * 4 + 2) * Hh, agg2, h2, N2n, relu);
    }

    // --- pooling + final linear ---
    graph_bounds<<<(Bn + 1 + 255) / 256, 256, 0, stream>>>(batch_central, NCn, bounds);
    graph_bounds<<<(Bn + 1 + 255) / 256, 256, 0, stream>>>(batch_cont,    N1n, bounds + (Bn + 1));
    graph_bounds<<<(Bn + 1 + 255) / 256, 256, 0, stream>>>(batch_categ,   N2n, bounds + 2 * (Bn + 1));
    pool_mean<<<Bn, 64, 0, stream>>>(hc, bounds,                pooled);
    pool_mean<<<Bn, 64, 0, stream>>>(h1, bounds + (Bn + 1),     pooled + Bn * Hh);
    pool_mean<<<Bn, 64, 0, stream>>>(h2, bounds + 2 * (Bn + 1), pooled + 2 * Bn * Hh);
    final_kernel<<<Bn, 128, 0, stream>>>(pooled, pooled + Bn * Hh, pooled + 2 * Bn * Hh, Wg, bg, out);
}

// Round 2
// 1076.401 us; speedup vs baseline: 1.0441x; 1.0441x over previous
//
#include <hip/hip_runtime.h>

#define Hh   256
#define NCn  20000
#define N1n  60000
#define N2n  60000
#define En   200000
#define Bn   512
#define OUTn 128

using bf16x8 = __attribute__((ext_vector_type(8))) __bf16;
using f32x4  = __attribute__((ext_vector_type(4))) float;

__device__ __forceinline__ float bf2f(unsigned short u) {
    union { unsigned int i; float f; } v; v.i = ((unsigned int)u) << 16; return v.f;
}
__device__ __forceinline__ unsigned short f2bf(float f) {
    union { float f; unsigned int i; } v; v.f = f;
    unsigned int r = v.i + 0x7FFFu + ((v.i >> 16) & 1u);
    return (unsigned short)(r >> 16);
}

// ---------------- input projection: out_bf16[M][256] = X[M][K] @ W[K][256] + b ----------
template<int K>
__global__ void proj_kernel(const float* __restrict__ X, const float* __restrict__ W,
                            const float* __restrict__ b, unsigned short* __restrict__ out) {
    __shared__ float xs[K];
    int m = blockIdx.x;
    int n = threadIdx.x;
    if (threadIdx.x < K) xs[threadIdx.x] = X[(size_t)m * K + threadIdx.x];
    __syncthreads();
    float acc = b[n];
#pragma unroll
    for (int k = 0; k < K; ++k) acc = fmaf(xs[k], W[k * Hh + n], acc);
    out[(size_t)m * Hh + n] = f2bf(acc);
}

// ---------------- weight prep: Wt[n][k] = W[k][n] * scale (bf16) ------------------------
__global__ void wt_prep(const float* __restrict__ W, float scale, unsigned short* __restrict__ Wt) {
    int idx = blockIdx.x * 256 + threadIdx.x;          // 65536
    int n = idx >> 8, k = idx & 255;
    Wt[idx] = f2bf(W[k * Hh + n] * scale);
}

// central concatenated weight: K=768 = [0.5*Wm1 ; 0.5*Wm3 ; 0.5*(Wr1+Wr3)], transposed
__global__ void wt_cat_prep(const float* __restrict__ Wm1, const float* __restrict__ Wm3,
                            const float* __restrict__ Wr1, const float* __restrict__ Wr3,
                            unsigned short* __restrict__ Wt) {
    int idx = blockIdx.x * 256 + threadIdx.x;          // 256*768
    int n = idx / 768, k = idx - n * 768;
    float v;
    if (k < 256)      v = 0.5f * Wm1[k * Hh + n];
    else if (k < 512) v = 0.5f * Wm3[(k - 256) * Hh + n];
    else              v = 0.5f * (Wr1[(k - 512) * Hh + n] + Wr3[(k - 512) * Hh + n]);
    Wt[idx] = f2bf(v);
}

__global__ void bias_central_prep(const float* __restrict__ b_msg, float* __restrict__ out) {
    int i = blockIdx.x * 256 + threadIdx.x;            // 512
    if (i >= 512) return;
    int l = i >> 8, n = i & 255;
    out[i] = 0.5f * (b_msg[(l * 4 + 1) * Hh + n] + b_msg[(l * 4 + 3) * Hh + n]);
}

// ---------------- CSR build ------------------------------------------------------------
__global__ void zero_i32(int* p, int n) {
    int i = blockIdx.x * 256 + threadIdx.x; if (i < n) p[i] = 0;
}
__global__ void deg_count(const int* __restrict__ dst, int* deg, int e) {
    int i = blockIdx.x * 256 + threadIdx.x; if (i < e) atomicAdd(&deg[dst[i]], 1);
}
__global__ void __launch_bounds__(1024) scan_chunk(const int* __restrict__ deg, int n,
                                                   int* __restrict__ rowptr, int* __restrict__ partials) {
    __shared__ int sh[1024];
    int tid = threadIdx.x;
    int i = blockIdx.x * 1024 + tid;
    int v = (i < n) ? deg[i] : 0;
    sh[tid] = v; __syncthreads();
    for (int off = 1; off < 1024; off <<= 1) {
        int t = (tid >= off) ? sh[tid - off] : 0; __syncthreads();
        sh[tid] += t; __syncthreads();
    }
    if (i < n) rowptr[i] = sh[tid] - v;       // exclusive within chunk
    if (tid == 1023) partials[blockIdx.x] = sh[1023];
}
__global__ void scan_partials(int* partials, int nchunks) {   // 1 block, 64 threads
    __shared__ int sh[64];
    int tid = threadIdx.x;
    int v = (tid < nchunks) ? partials[tid] : 0;
    sh[tid] = v; __syncthreads();
    for (int off = 1; off < 64; off <<= 1) {
        int t = (tid >= off) ? sh[tid - off] : 0; __syncthreads();
        sh[tid] += t; __syncthreads();
    }
    if (tid < nchunks) partials[tid] = sh[tid] - v;           // exclusive
}
__global__ void __launch_bounds__(1024) scan_add(int* rowptr, const int* __restrict__ partials,
                                                 int n, int e_total) {
    int i = blockIdx.x * 1024 + threadIdx.x;
    if (i < n) rowptr[i] += partials[blockIdx.x];
    if (blockIdx.x == 0 && threadIdx.x == 0) rowptr[n] = e_total;
}
__global__ void scatter_edges(const int* __restrict__ src, const int* __restrict__ dst,
                              const int* __restrict__ rowptr, int* fill, int* colsrc, int e) {
    int i = blockIdx.x * 256 + threadIdx.x;
    if (i < e) {
        int d = dst[i];
        int pos = rowptr[d] + atomicAdd(&fill[d], 1);
        colsrc[pos] = src[i];
    }
}

// ---------------- gather-based segment mean: one wave per dst node ---------------------
__global__ void agg_mean(const unsigned short* __restrict__ feat,
                         const int* __restrict__ rowptr, const int* __restrict__ colsrc,
                         unsigned short* __restrict__ out, int ostride, int ocol, int n_dst) {
    int gw = (blockIdx.x * blockDim.x + threadIdx.x) >> 6;
    int lane = threadIdx.x & 63;
    if (gw >= n_dst) return;
    int s = rowptr[gw], e = rowptr[gw + 1];
    float a0 = 0.f, a1 = 0.f, a2 = 0.f, a3 = 0.f;
    for (int i = s; i < e; ++i) {
        int sc = colsrc[i];
        ushort4 v = *reinterpret_cast<const ushort4*>(feat + (size_t)sc * Hh + lane * 4);
        a0 += bf2f(v.x); a1 += bf2f(v.y); a2 += bf2f(v.z); a3 += bf2f(v.w);
    }
    int c = e - s;
    float inv = 1.0f / (float)(c > 1 ? c : 1);
    ushort4 o;
    o.x = f2bf(a0 * inv); o.y = f2bf(a1 * inv); o.z = f2bf(a2 * inv); o.w = f2bf(a3 * inv);
    *reinterpret_cast<ushort4*>(out + (size_t)gw * ostride + ocol + lane * 4) = o;
}

// copy current central features into cat[:, 512:768]
__global__ void copy_to_cat(const unsigned short* __restrict__ hc, unsigned short* __restrict__ cat) {
    int idx = blockIdx.x * 256 + threadIdx.x;   // NC*32 threads, 8 elems each
    int m = idx >> 5, c = (idx & 31) * 8;
    *reinterpret_cast<uint4*>(cat + (size_t)m * 768 + 512 + c) =
        *reinterpret_cast<const uint4*>(hc + (size_t)m * Hh + c);
}

// ---------------- main GEMM: barrier-free, LDS-free, direct-to-register fragments ------
// C[M][256] = A[M][K] @ W  (Wt[n][k] = W^T bf16), + bias + Add + optional relu.
// Block = 256 thr = 4 waves; block tile 64 rows x 256 cols; wave tile 64x64 (4x4 MFMA).
// Operand-swapped MFMA: acc = mfma(b_frag, a_frag, acc) so lane l holds
// C[rbase + (l&15)][cbase + (l>>4)*4 + j] -> contiguous ushort4 stores.
template<int KSTEPS, bool RELU, bool HASADD>
__global__ void __launch_bounds__(256) gemm_dir(const unsigned short* __restrict__ A, int lda,
                                                const unsigned short* __restrict__ Wt,
                                                const float* __restrict__ bias,
                                                const unsigned short* __restrict__ Add,
                                                unsigned short* __restrict__ C, int M) {
    constexpr int K = KSTEPS * 32;
    const int tid = threadIdx.x;
    const int wid = tid >> 6, lane = tid & 63;
    const int llo = lane & 15, lhi = lane >> 4;
    const int m0 = blockIdx.x * 64;
    const int cb = wid * 64;

    // per-fragment base pointers (rows clamped for the M tail; garbage rows never stored)
    const unsigned short* pA[4];
#pragma unroll
    for (int rt = 0; rt < 4; ++rt) {
        int r = m0 + rt * 16 + llo;
        pA[rt] = A + (size_t)(r < M ? r : M - 1) * lda + lhi * 8;
    }
    const unsigned short* pB[4];
#pragma unroll
    for (int ct = 0; ct < 4; ++ct)
        pB[ct] = Wt + (size_t)(cb + ct * 16 + llo) * K + lhi * 8;

    f32x4 acc[4][4] = {};

    bf16x8 aX[4], bX[4], aY[4], bY[4];
    auto LD = [&](bf16x8 (&a)[4], bf16x8 (&b)[4], int ks) {
        if (ks < KSTEPS) {
            const int ko = ks * 32;
#pragma unroll
            for (int t = 0; t < 4; ++t) {
                a[t] = *reinterpret_cast<const bf16x8*>(pA[t] + ko);
                b[t] = *reinterpret_cast<const bf16x8*>(pB[t] + ko);
            }
        }
    };
    auto FM = [&](bf16x8 (&a)[4], bf16x8 (&b)[4]) {
#pragma unroll
        for (int rt = 0; rt < 4; ++rt)
#pragma unroll
            for (int ct = 0; ct < 4; ++ct)
                acc[rt][ct] = __builtin_amdgcn_mfma_f32_16x16x32_bf16(b[ct], a[rt], acc[rt][ct], 0, 0, 0);
    };

    LD(aX, bX, 0);
#pragma unroll
    for (int ks = 0; ks < KSTEPS; ks += 2) {
        LD(aY, bY, ks + 1);
        FM(aX, bX);
        LD(aX, bX, ks + 2);
        FM(aY, bY);
    }

    // epilogue: lane holds rows llo, 4 consecutive cols at cb + ct*16 + lhi*4
#pragma unroll
    for (int rt = 0; rt < 4; ++rt) {
        const int row = m0 + rt * 16 + llo;
        if (row < M) {
#pragma unroll
            for (int ct = 0; ct < 4; ++ct) {
                const int col0 = cb + ct * 16 + lhi * 4;
                float v0 = acc[rt][ct][0], v1 = acc[rt][ct][1], v2 = acc[rt][ct][2], v3 = acc[rt][ct][3];
                if (bias) {
                    float4 bv = *reinterpret_cast<const float4*>(bias + col0);
                    v0 += bv.x; v1 += bv.y; v2 += bv.z; v3 += bv.w;
                }
                if (HASADD) {
                    ushort4 ad = *reinterpret_cast<const ushort4*>(Add + (size_t)row * Hh + col0);
                    v0 += bf2f(ad.x); v1 += bf2f(ad.y); v2 += bf2f(ad.z); v3 += bf2f(ad.w);
                }
                if (RELU) {
                    v0 = fmaxf(v0, 0.f); v1 = fmaxf(v1, 0.f); v2 = fmaxf(v2, 0.f); v3 = fmaxf(v3, 0.f);
                }
                ushort4 o;
                o.x = f2bf(v0); o.y = f2bf(v1); o.z = f2bf(v2); o.w = f2bf(v3);
                *reinterpret_cast<ushort4*>(C + (size_t)row * Hh + col0) = o;
            }
        }
    }
}

// ---------------- pooling --------------------------------------------------------------
__global__ void graph_bounds(const int* __restrict__ batch, int n, int* __restrict__ bound) {
    int b = blockIdx.x * 256 + threadIdx.x;
    if (b > Bn) return;
    int lo = 0, hi = n;
    while (lo < hi) { int mid = (lo + hi) >> 1; if (batch[mid] < b) lo = mid + 1; else hi = mid; }
    bound[b] = lo;
}
__global__ void pool_mean(const unsigned short* __restrict__ feat, const int* __restrict__ bound,
                          float* __restrict__ outp) {
    int g = blockIdx.x, lane = threadIdx.x;   // 64 threads
    int s = bound[g], e = bound[g + 1];
    float a0 = 0.f, a1 = 0.f, a2 = 0.f, a3 = 0.f;
    for (int i = s; i < e; ++i) {
        ushort4 v = *reinterpret_cast<const ushort4*>(feat + (size_t)i * Hh + lane * 4);
        a0 += bf2f(v.x); a1 += bf2f(v.y); a2 += bf2f(v.z); a3 += bf2f(v.w);
    }
    int c = e - s;
    float inv = 1.0f / (float)(c > 1 ? c : 1);
    float* op = outp + (size_t)g * Hh + lane * 4;
    op[0] = a0 * inv; op[1] = a1 * inv; op[2] = a2 * inv; op[3] = a3 * inv;
}
__global__ void final_kernel(const float* __restrict__ p0, const float* __restrict__ p1,
                             const float* __restrict__ p2, const float* __restrict__ Wg,
                             const float* __restrict__ bg, float* __restrict__ out) {
    __shared__ float emb[Hh];
    int g = blockIdx.x, o = threadIdx.x;     // 128 threads
    for (int k = o; k < Hh; k += 128)
        emb[k] = (p0[g * Hh + k] + p1[g * Hh + k] + p2[g * Hh + k]) * (1.0f / 3.0f);
    __syncthreads();
    float acc = bg[o];
#pragma unroll 8
    for (int k = 0; k < Hh; ++k) acc = fmaf(emb[k], Wg[k * OUTn + o], acc);
    out[(size_t)g * OUTn + o] = acc;
}

// ---------------- host orchestration ----------------------------------------------------
extern "C" void kernel_launch(void* const* d_in, const int* in_sizes, int n_in,
                              void* d_out, int out_size, void* d_ws, size_t ws_size,
                              hipStream_t stream) {
    const float* x_central = (const float*)d_in[0];
    const float* x_cont    = (const float*)d_in[1];
    const float* x_categ   = (const float*)d_in[2];
    const int* ei_c2cont   = (const int*)d_in[3];
    const int* ei_cont2c   = (const int*)d_in[4];
    const int* ei_c2categ  = (const int*)d_in[5];
    const int* ei_categ2c  = (const int*)d_in[6];
    const int* batch_central = (const int*)d_in[7];
    const int* batch_cont    = (const int*)d_in[8];
    const int* batch_categ   = (const int*)d_in[9];
    const float* Wp_central = (const float*)d_in[11];
    const float* bp_central = (const float*)d_in[12];
    const float* Wp_cont    = (const float*)d_in[13];
    const float* bp_cont    = (const float*)d_in[14];
    const float* Wp_categ   = (const float*)d_in[15];
    const float* bp_categ   = (const float*)d_in[16];
    const float* W_msg  = (const float*)d_in[17];
    const float* b_msg  = (const float*)d_in[18];
    const float* W_root = (const float*)d_in[19];
    const float* Wg     = (const float*)d_in[20];
    const float* bg     = (const float*)d_in[21];
    float* out = (float*)d_out;

    char* base = (char*)d_ws;
    size_t off = 0;
    auto alloc = [&](size_t bytes) -> void* {
        off = (off + 255) & ~(size_t)255;
        void* p = base + off; off += bytes; return p;
    };

    unsigned short* hc   = (unsigned short*)alloc((size_t)NCn * Hh * 2);
    unsigned short* h1   = (unsigned short*)alloc((size_t)N1n * Hh * 2);
    unsigned short* h2   = (unsigned short*)alloc((size_t)N2n * Hh * 2);
    unsigned short* t0   = (unsigned short*)alloc((size_t)NCn * Hh * 2);
    unsigned short* t2   = (unsigned short*)alloc((size_t)NCn * Hh * 2);
    unsigned short* cat  = (unsigned short*)alloc((size_t)NCn * 768 * 2);
    unsigned short* agg0 = (unsigned short*)alloc((size_t)N1n * Hh * 2);
    unsigned short* agg2 = (unsigned short*)alloc((size_t)N2n * Hh * 2);

    unsigned short *Wt_msg0[2], *Wt_msg2[2], *Wt_root0[2], *Wt_root2[2], *Wt_cat[2];
    for (int l = 0; l < 2; ++l) {
        Wt_msg0[l]  = (unsigned short*)alloc(65536 * 2);
        Wt_msg2[l]  = (unsigned short*)alloc(65536 * 2);
        Wt_root0[l] = (unsigned short*)alloc(65536 * 2);
        Wt_root2[l] = (unsigned short*)alloc(65536 * 2);
        Wt_cat[l]   = (unsigned short*)alloc(768 * 256 * 2);
    }
    float* b_central = (float*)alloc(512 * 4);

    const int nd[4] = { N1n, NCn, N2n, NCn };
    const int* eis[4] = { ei_c2cont, ei_cont2c, ei_c2categ, ei_categ2c };
    int* rp[4]; int* cs[4];
    for (int r = 0; r < 4; ++r) {
        rp[r] = (int*)alloc((size_t)(nd[r] + 1) * 4);
        cs[r] = (int*)alloc((size_t)En * 4);
    }
    int* tmp      = (int*)alloc((size_t)60000 * 4);
    int* partials = (int*)alloc(64 * 4);
    float* pooled = (float*)alloc((size_t)3 * Bn * Hh * 4);
    int* bounds   = (int*)alloc((size_t)3 * (Bn + 1) * 4);
    (void)ws_size; (void)in_sizes; (void)n_in; (void)out_size;

    // --- weight prep ---
    for (int l = 0; l < 2; ++l) {
        const float* Wm = W_msg  + (size_t)l * 4 * 65536;
        const float* Wr = W_root + (size_t)l * 4 * 65536;
        wt_prep<<<256, 256, 0, stream>>>(Wm + 0 * 65536, 1.0f, Wt_msg0[l]);
        wt_prep<<<256, 256, 0, stream>>>(Wm + 2 * 65536, 1.0f, Wt_msg2[l]);
        wt_prep<<<256, 256, 0, stream>>>(Wr + 0 * 65536, 1.0f, Wt_root0[l]);
        wt_prep<<<256, 256, 0, stream>>>(Wr + 2 * 65536, 1.0f, Wt_root2[l]);
        wt_cat_prep<<<768, 256, 0, stream>>>(Wm + 1 * 65536, Wm + 3 * 65536,
                                             Wr + 1 * 65536, Wr + 3 * 65536, Wt_cat[l]);
    }
    bias_central_prep<<<2, 256, 0, stream>>>(b_msg, b_central);

    // --- input projections ---
    proj_kernel<64><<<NCn, 256, 0, stream>>>(x_central, Wp_central, bp_central, hc);
    proj_kernel<16><<<N1n, 256, 0, stream>>>(x_cont,    Wp_cont,    bp_cont,    h1);
    proj_kernel<16><<<N2n, 256, 0, stream>>>(x_categ,   Wp_categ,   bp_categ,   h2);

    // --- CSR build (shared by both layers) ---
    for (int r = 0; r < 4; ++r) {
        int n = nd[r];
        int nblk = (n + 255) / 256;
        int nch  = (n + 1023) / 1024;
        zero_i32<<<nblk, 256, 0, stream>>>(tmp, n);
        deg_count<<<(En + 255) / 256, 256, 0, stream>>>(eis[r] + En, tmp, En);
        scan_chunk<<<nch, 1024, 0, stream>>>(tmp, n, rp[r], partials);
        scan_partials<<<1, 64, 0, stream>>>(partials, nch);
        scan_add<<<nch, 1024, 0, stream>>>(rp[r], partials, n, En);
        zero_i32<<<nblk, 256, 0, stream>>>(tmp, n);
        scatter_edges<<<(En + 255) / 256, 256, 0, stream>>>(eis[r], eis[r] + En, rp[r], tmp, cs[r], En);
    }

    // --- GNN layers ---
    for (int l = 0; l < 2; ++l) {
        bool relu = (l == 0);
        // transform central on the small side for outgoing messages (K=256, no bias/add)
        gemm_dir<8, false, false><<<(NCn + 63) / 64, 256, 0, stream>>>(hc, Hh, Wt_msg0[l], nullptr, nullptr, t0, NCn);
        gemm_dir<8, false, false><<<(NCn + 63) / 64, 256, 0, stream>>>(hc, Hh, Wt_msg2[l], nullptr, nullptr, t2, NCn);
        // aggregate children -> central into cat[:,0:256] and [:,256:512]
        agg_mean<<<(NCn * 64 + 255) / 256, 256, 0, stream>>>(h1, rp[1], cs[1], cat, 768, 0,   NCn);
        agg_mean<<<(NCn * 64 + 255) / 256, 256, 0, stream>>>(h2, rp[3], cs[3], cat, 768, 256, NCn);
        copy_to_cat<<<(NCn * 32) / 256, 256, 0, stream>>>(hc, cat);
        // aggregate transformed central -> children
        agg_mean<<<(N1n * 64 + 255) / 256, 256, 0, stream>>>(t0, rp[0], cs[0], agg0, 256, 0, N1n);
        agg_mean<<<(N2n * 64 + 255) / 256, 256, 0, stream>>>(t2, rp[2], cs[2], agg2, 256, 0, N2n);
        // updates (in-place safe: each block reads only its own 64 rows)
        if (relu) {
            gemm_dir<24, true, false><<<(NCn + 63) / 64, 256, 0, stream>>>(cat, 768, Wt_cat[l], b_central + l * 256, nullptr, hc, NCn);
            gemm_dir<8, true, true><<<(N1n + 63) / 64, 256, 0, stream>>>(h1, Hh, Wt_root0[l], b_msg + (l * 4 + 0) * Hh, agg0, h1, N1n);
            gemm_dir<8, true, true><<<(N2n + 63) / 64, 256, 0, stream>>>(h2, Hh, Wt_root2[l], b_msg + (l * 4 + 2) * Hh, agg2, h2, N2n);
        } else {
            gemm_dir<24, false, false><<<(NCn + 63) / 64, 256, 0, stream>>>(cat, 768, Wt_cat[l], b_central + l * 256, nullptr, hc, NCn);
            gemm_dir<8, false, true><<<(N1n + 63) / 64, 256, 0, stream>>>(h1, Hh, Wt_root0[l], b_msg + (l * 4 + 0) * Hh, agg0, h1, N1n);
            gemm_dir<8, false, true><<<(N2n + 63) / 64, 256, 0, stream>>>(h2, Hh, Wt_root2[l], b_msg + (l * 4 + 2) * Hh, agg2, h2, N2n);
        }
    }

    // --- pooling + final linear ---
    graph_bounds<<<(Bn + 1 + 255) / 256, 256, 0, stream>>>(batch_central, NCn, bounds);
    graph_bounds<<<(Bn + 1 + 255) / 256, 256, 0, stream>>>(batch_cont,    N1n, bounds + (Bn + 1));
    graph_bounds<<<(Bn + 1 + 255) / 256, 256, 0, stream>>>(batch_categ,   N2n, bounds + 2 * (Bn + 1));
    pool_mean<<<Bn, 64, 0, stream>>>(hc, bounds,                pooled);
    pool_mean<<<Bn, 64, 0, stream>>>(h1, bounds + (Bn + 1),     pooled + Bn * Hh);
    pool_mean<<<Bn, 64, 0, stream>>>(h2, bounds + 2 * (Bn + 1), pooled + 2 * Bn * Hh);
    final_kernel<<<Bn, 128, 0, stream>>>(pooled, pooled + Bn * Hh, pooled + 2 * Bn * Hh, Wg, bg, out);
}

// Round 3
// 845.938 us; speedup vs baseline: 1.3285x; 1.2724x over previous
//
#include <hip/hip_runtime.h>

#define Hh   256
#define NCn  20000
#define N1n  60000
#define N2n  60000
#define En   200000
#define Bn   512
#define OUTn 128

using bf16x8 = __attribute__((ext_vector_type(8))) __bf16;
using f32x4  = __attribute__((ext_vector_type(4))) float;

__device__ __forceinline__ float bf2f(unsigned short u) {
    union { unsigned int i; float f; } v; v.i = ((unsigned int)u) << 16; return v.f;
}
__device__ __forceinline__ unsigned short f2bf(float f) {
    union { float f; unsigned int i; } v; v.f = f;
    unsigned int r = v.i + 0x7FFFu + ((v.i >> 16) & 1u);
    return (unsigned short)(r >> 16);
}

struct CPtr4 { const int* p[4]; };
struct IPtr4 { int* p[4]; };
struct AggDesc {
    const unsigned short* feat;
    const int* rowptr;
    const int* colsrc;
    unsigned short* out;
    int fstride, ostride, ocol, n_dst;
};
struct GemmDesc {
    const unsigned short* A;
    const unsigned short* Wt;
    const float* bias;
    const unsigned short* Add;
    unsigned short* C;
};

// ---------------- weight prep ----------------------------------------------------------
// 8 transposed 256x256 weights: mat = l*4 + {0:msg0, 1:msg2, 2:root0, 3:root2}
__global__ void wt8_prep(const float* __restrict__ Wm, const float* __restrict__ Wr,
                         unsigned short* __restrict__ Wt8) {
    int idx = blockIdx.x * 256 + threadIdx.x;      // 524288
    int mat = idx >> 16, w = idx & 65535;
    int n = w >> 8, k = w & 255;
    int l = mat >> 2, sel = mat & 3;
    const float* src = (sel < 2) ? Wm : Wr;
    int r = (sel & 1) * 2;                          // 0 or 2
    Wt8[idx] = f2bf(src[((size_t)(l * 4 + r)) * 65536 + k * 256 + n]);
}
// central concat weight [256][768] transposed + central bias
__global__ void wtcat_prep(const float* __restrict__ Wm, const float* __restrict__ Wr,
                           const float* __restrict__ bm, unsigned short* __restrict__ Wtc,
                           float* __restrict__ b_central) {
    int idx = blockIdx.x * 256 + threadIdx.x;      // 393728 total
    if (idx < 393216) {
        int l = idx / 196608; int w = idx - l * 196608;
        int n = w / 768; int k = w - n * 768;
        const float* WmL = Wm + (size_t)l * 4 * 65536;
        const float* WrL = Wr + (size_t)l * 4 * 65536;
        float v;
        if (k < 256)      v = 0.5f * WmL[1 * 65536 + k * 256 + n];
        else if (k < 512) v = 0.5f * WmL[3 * 65536 + (k - 256) * 256 + n];
        else              v = 0.5f * (WrL[1 * 65536 + (k - 512) * 256 + n] +
                                      WrL[3 * 65536 + (k - 512) * 256 + n]);
        Wtc[idx] = f2bf(v);
    } else if (idx < 393728) {
        int i = idx - 393216; int l = i >> 8, n = i & 255;
        b_central[i] = 0.5f * (bm[(l * 4 + 1) * Hh + n] + bm[(l * 4 + 3) * Hh + n]);
    }
}

// ---------------- input projections ----------------------------------------------------
template<int K>
__global__ void proj_kernel(const float* __restrict__ X, const float* __restrict__ W,
                            const float* __restrict__ b, unsigned short* __restrict__ out) {
    __shared__ float xs[K];
    int m = blockIdx.x;
    int n = threadIdx.x;
    if (threadIdx.x < K) xs[threadIdx.x] = X[(size_t)m * K + threadIdx.x];
    __syncthreads();
    float acc = b[n];
#pragma unroll
    for (int k = 0; k < K; ++k) acc = fmaf(xs[k], W[k * Hh + n], acc);
    out[(size_t)m * Hh + n] = f2bf(acc);
}
__global__ void proj_child(const float* __restrict__ X1, const float* __restrict__ W1,
                           const float* __restrict__ b1, unsigned short* __restrict__ o1,
                           const float* __restrict__ X2, const float* __restrict__ W2,
                           const float* __restrict__ b2, unsigned short* __restrict__ o2) {
    __shared__ float xs[16];
    int m = blockIdx.x;
    const float *X, *W, *b; unsigned short* o; int mm;
    if (m < N1n) { X = X1; W = W1; b = b1; o = o1; mm = m; }
    else         { X = X2; W = W2; b = b2; o = o2; mm = m - N1n; }
    int n = threadIdx.x;
    if (n < 16) xs[n] = X[(size_t)mm * 16 + n];
    __syncthreads();
    float acc = b[n];
#pragma unroll
    for (int k = 0; k < 16; ++k) acc = fmaf(xs[k], W[k * Hh + n], acc);
    o[(size_t)mm * Hh + n] = f2bf(acc);
}

// ---------------- CSR build (relation-batched) -----------------------------------------
// rel order: 0: c2cont (dst N1), 1: cont2c (dst NC), 2: c2categ (dst N2), 3: categ2c (dst NC)
__device__ __forceinline__ int degoff_of(int rel) {
    const int t[4] = { 0, N1n, N1n + NCn, N1n + NCn + N2n };
    return t[rel];
}
__device__ __forceinline__ int nrel_of(int rel) {
    const int t[4] = { N1n, NCn, N2n, NCn };
    return t[rel];
}
__device__ __forceinline__ void rel_chunk(int b, int& rel, int& c) {
    if (b < 59)       { rel = 0; c = b; }
    else if (b < 79)  { rel = 1; c = b - 59; }
    else if (b < 138) { rel = 2; c = b - 79; }
    else              { rel = 3; c = b - 138; }
}

__global__ void zero_i32(int* p, int n) {
    int i = blockIdx.x * 256 + threadIdx.x; if (i < n) p[i] = 0;
}
__global__ void deg_count_all(CPtr4 dst, int* __restrict__ deg_all) {
    int i = blockIdx.x * 256 + threadIdx.x;
    if (i >= 4 * En) return;
    int rel = i / En; int e = i - rel * En;
    atomicAdd(&deg_all[degoff_of(rel) + dst.p[rel][e]], 1);
}
__global__ void __launch_bounds__(1024) scan_chunk_all(const int* __restrict__ deg_all,
                                                       IPtr4 rp, int* __restrict__ partials) {
    int rel, c; rel_chunk(blockIdx.x, rel, c);
    int n = nrel_of(rel);
    __shared__ int sh[1024];
    int tid = threadIdx.x;
    int i = c * 1024 + tid;
    int v = (i < n) ? deg_all[degoff_of(rel) + i] : 0;
    sh[tid] = v; __syncthreads();
    for (int off = 1; off < 1024; off <<= 1) {
        int t = (tid >= off) ? sh[tid - off] : 0; __syncthreads();
        sh[tid] += t; __syncthreads();
    }
    if (i < n) rp.p[rel][i] = sh[tid] - v;
    if (tid == 1023) partials[rel * 64 + c] = sh[1023];
}
__global__ void scan_partials_all(int* partials) {   // grid 4 x 64 threads
    const int nch[4] = { 59, 20, 59, 20 };
    int rel = blockIdx.x;
    __shared__ int sh[64];
    int tid = threadIdx.x;
    int v = (tid < nch[rel]) ? partials[rel * 64 + tid] : 0;
    sh[tid] = v; __syncthreads();
    for (int off = 1; off < 64; off <<= 1) {
        int t = (tid >= off) ? sh[tid - off] : 0; __syncthreads();
        sh[tid] += t; __syncthreads();
    }
    if (tid < nch[rel]) partials[rel * 64 + tid] = sh[tid] - v;
}
__global__ void __launch_bounds__(1024) scan_add_all(IPtr4 rp, const int* __restrict__ partials) {
    int rel, c; rel_chunk(blockIdx.x, rel, c);
    int n = nrel_of(rel);
    int tid = threadIdx.x;
    int i = c * 1024 + tid;
    if (i < n) rp.p[rel][i] += partials[rel * 64 + c];
    if (c == 0 && tid == 0) rp.p[rel][n] = En;
}
__global__ void scatter_all(CPtr4 src, CPtr4 dst, CPtr4 rp, int* fill_all, IPtr4 cs) {
    int i = blockIdx.x * 256 + threadIdx.x;
    if (i >= 4 * En) return;
    int rel = i / En; int e = i - rel * En;
    int d = dst.p[rel][e];
    int pos = rp.p[rel][d] + atomicAdd(&fill_all[degoff_of(rel) + d], 1);
    cs.p[rel][pos] = src.p[rel][e];
}

// ---------------- gather-based segment mean (multi-descriptor) -------------------------
__global__ void agg_all(AggDesc d0, AggDesc d1, AggDesc d2) {
    AggDesc d = (blockIdx.y == 0) ? d0 : (blockIdx.y == 1) ? d1 : d2;
    int gw = (blockIdx.x * blockDim.x + threadIdx.x) >> 6;
    int lane = threadIdx.x & 63;
    if (gw >= d.n_dst) return;
    if (d.rowptr == nullptr) {                         // identity copy slot
        *reinterpret_cast<ushort4*>(d.out + (size_t)gw * d.ostride + d.ocol + lane * 4) =
            *reinterpret_cast<const ushort4*>(d.feat + (size_t)gw * d.fstride + lane * 4);
        return;
    }
    int s = d.rowptr[gw], e = d.rowptr[gw + 1];
    float a0 = 0.f, a1 = 0.f, a2 = 0.f, a3 = 0.f;
    for (int i = s; i < e; ++i) {
        int sc = d.colsrc[i];
        ushort4 v = *reinterpret_cast<const ushort4*>(d.feat + (size_t)sc * d.fstride + lane * 4);
        a0 += bf2f(v.x); a1 += bf2f(v.y); a2 += bf2f(v.z); a3 += bf2f(v.w);
    }
    int c = e - s;
    float inv = 1.0f / (float)(c > 1 ? c : 1);
    ushort4 o;
    o.x = f2bf(a0 * inv); o.y = f2bf(a1 * inv); o.z = f2bf(a2 * inv); o.w = f2bf(a3 * inv);
    *reinterpret_cast<ushort4*>(d.out + (size_t)gw * d.ostride + d.ocol + lane * 4) = o;
}

// ---------------- GEMM: barrier-free, BM=32 rows/block, direct register fragments ------
// C[.][col] += A[MxK] @ W^T; operand-swapped MFMA so stores are contiguous ushort4.
template<int KSTEPS, bool RELU, bool HASADD>
__device__ __forceinline__ void gemm_body(const unsigned short* __restrict__ A, int lda,
                                          const unsigned short* __restrict__ Wt,
                                          const float* __restrict__ bias,
                                          const unsigned short* __restrict__ Add, int lad,
                                          unsigned short* __restrict__ C, int ldc,
                                          int M, int m0, int cb_base) {
    constexpr int K = KSTEPS * 32;
    const int tid = threadIdx.x;
    const int wid = tid >> 6, lane = tid & 63;
    const int llo = lane & 15, lhi = lane >> 4;
    const int cb = cb_base + wid * 64;

    const unsigned short* pA[2];
#pragma unroll
    for (int rt = 0; rt < 2; ++rt) {
        int r = m0 + rt * 16 + llo;
        pA[rt] = A + (size_t)(r < M ? r : M - 1) * lda + lhi * 8;
    }
    const unsigned short* pB[4];
#pragma unroll
    for (int ct = 0; ct < 4; ++ct)
        pB[ct] = Wt + (size_t)(cb + ct * 16 + llo) * K + lhi * 8;

    f32x4 acc[2][4] = {};
    bf16x8 aX[2], bX[4], aY[2], bY[4];

    auto LD = [&](bf16x8 (&a)[2], bf16x8 (&b)[4], int ks) {
        if (ks < KSTEPS) {
            const int ko = ks * 32;
#pragma unroll
            for (int t = 0; t < 2; ++t) a[t] = *reinterpret_cast<const bf16x8*>(pA[t] + ko);
#pragma unroll
            for (int t = 0; t < 4; ++t) b[t] = *reinterpret_cast<const bf16x8*>(pB[t] + ko);
        }
    };
    auto FM = [&](bf16x8 (&a)[2], bf16x8 (&b)[4]) {
#pragma unroll
        for (int rt = 0; rt < 2; ++rt)
#pragma unroll
            for (int ct = 0; ct < 4; ++ct)
                acc[rt][ct] = __builtin_amdgcn_mfma_f32_16x16x32_bf16(b[ct], a[rt], acc[rt][ct], 0, 0, 0);
    };

    LD(aX, bX, 0);
#pragma unroll
    for (int ks = 0; ks < KSTEPS; ks += 2) {
        LD(aY, bY, ks + 1);
        FM(aX, bX);
        LD(aX, bX, ks + 2);
        FM(aY, bY);
    }

#pragma unroll
    for (int rt = 0; rt < 2; ++rt) {
        const int row = m0 + rt * 16 + llo;
        if (row < M) {
#pragma unroll
            for (int ct = 0; ct < 4; ++ct) {
                const int col0 = cb + ct * 16 + lhi * 4;
                float v0 = acc[rt][ct][0], v1 = acc[rt][ct][1], v2 = acc[rt][ct][2], v3 = acc[rt][ct][3];
                if (bias) {
                    float4 bv = *reinterpret_cast<const float4*>(bias + col0);
                    v0 += bv.x; v1 += bv.y; v2 += bv.z; v3 += bv.w;
                }
                if (HASADD) {
                    ushort4 ad = *reinterpret_cast<const ushort4*>(Add + (size_t)row * lad + col0);
                    v0 += bf2f(ad.x); v1 += bf2f(ad.y); v2 += bf2f(ad.z); v3 += bf2f(ad.w);
                }
                if (RELU) {
                    v0 = fmaxf(v0, 0.f); v1 = fmaxf(v1, 0.f); v2 = fmaxf(v2, 0.f); v3 = fmaxf(v3, 0.f);
                }
                ushort4 o;
                o.x = f2bf(v0); o.y = f2bf(v1); o.z = f2bf(v2); o.w = f2bf(v3);
                *reinterpret_cast<ushort4*>(C + (size_t)row * ldc + col0) = o;
            }
        }
    }
}

template<int KSTEPS, bool RELU, bool HASADD>
__global__ void __launch_bounds__(256) gemm_dir(const unsigned short* __restrict__ A, int lda,
                                                const unsigned short* __restrict__ Wt,
                                                const float* __restrict__ bias,
                                                const unsigned short* __restrict__ Add, int lad,
                                                unsigned short* __restrict__ C, int ldc, int M) {
    gemm_body<KSTEPS, RELU, HASADD>(A, lda, Wt, bias, Add, lad, C, ldc, M,
                                    blockIdx.x * 32, blockIdx.y * 256);
}
template<int KSTEPS, bool RELU, bool HASADD>
__global__ void __launch_bounds__(256) gemm_pair(GemmDesc g0, GemmDesc g1,
                                                 int lda, int lad, int ldc, int M) {
    GemmDesc g = blockIdx.y ? g1 : g0;
    gemm_body<KSTEPS, RELU, HASADD>(g.A, lda, g.Wt, g.bias, g.Add, lad, g.C, ldc, M,
                                    blockIdx.x * 32, 0);
}

// ---------------- pooling + final linear (fused) ---------------------------------------
__global__ void graph_bounds_all(const int* __restrict__ bc, const int* __restrict__ b1,
                                 const int* __restrict__ b2, int* __restrict__ bound) {
    int idx = blockIdx.x * 256 + threadIdx.x;
    if (idx >= 3 * (Bn + 1)) return;
    int t = idx / (Bn + 1); int b = idx - t * (Bn + 1);
    const int* batch = (t == 0) ? bc : (t == 1) ? b1 : b2;
    int n = (t == 0) ? NCn : (t == 1) ? N1n : N2n;
    int lo = 0, hi = n;
    while (lo < hi) { int mid = (lo + hi) >> 1; if (batch[mid] < b) lo = mid + 1; else hi = mid; }
    bound[idx] = lo;
}
__global__ void __launch_bounds__(256) pool_final(const unsigned short* __restrict__ hc,
                                                  const unsigned short* __restrict__ h1,
                                                  const unsigned short* __restrict__ h2,
                                                  const int* __restrict__ bound,
                                                  const float* __restrict__ Wg,
                                                  const float* __restrict__ bg,
                                                  float* __restrict__ out) {
    __shared__ float sh[4][256];
    __shared__ float emb[256];
    int g = blockIdx.x;
    int tid = threadIdx.x, wid = tid >> 6, lane = tid & 63;
    const unsigned short* feats[3] = { hc, h1, h2 };
    float embacc = 0.f;
#pragma unroll
    for (int t = 0; t < 3; ++t) {
        int s = bound[t * (Bn + 1) + g], e = bound[t * (Bn + 1) + g + 1];
        float a0 = 0.f, a1 = 0.f, a2 = 0.f, a3 = 0.f;
        for (int i = s + wid; i < e; i += 4) {
            ushort4 v = *reinterpret_cast<const ushort4*>(feats[t] + (size_t)i * Hh + lane * 4);
            a0 += bf2f(v.x); a1 += bf2f(v.y); a2 += bf2f(v.z); a3 += bf2f(v.w);
        }
        sh[wid][lane * 4 + 0] = a0; sh[wid][lane * 4 + 1] = a1;
        sh[wid][lane * 4 + 2] = a2; sh[wid][lane * 4 + 3] = a3;
        __syncthreads();
        int c = e - s;
        float inv = (c > 0) ? (1.0f / (float)c) * (1.0f / 3.0f) : 0.0f;
        embacc += (sh[0][tid] + sh[1][tid] + sh[2][tid] + sh[3][tid]) * inv;
        __syncthreads();
    }
    emb[tid] = embacc;
    __syncthreads();
    int o = tid & 127, half = tid >> 7;
    float acc = 0.f;
#pragma unroll 8
    for (int k = half * 128; k < half * 128 + 128; ++k) acc = fmaf(emb[k], Wg[k * OUTn + o], acc);
    sh[0][tid] = acc;
    __syncthreads();
    if (tid < 128) out[(size_t)g * OUTn + tid] = sh[0][tid] + sh[0][128 + tid] + bg[tid];
}

// ---------------- host orchestration ----------------------------------------------------
extern "C" void kernel_launch(void* const* d_in, const int* in_sizes, int n_in,
                              void* d_out, int out_size, void* d_ws, size_t ws_size,
                              hipStream_t stream) {
    const float* x_central = (const float*)d_in[0];
    const float* x_cont    = (const float*)d_in[1];
    const float* x_categ   = (const float*)d_in[2];
    const int* ei_c2cont   = (const int*)d_in[3];
    const int* ei_cont2c   = (const int*)d_in[4];
    const int* ei_c2categ  = (const int*)d_in[5];
    const int* ei_categ2c  = (const int*)d_in[6];
    const int* batch_central = (const int*)d_in[7];
    const int* batch_cont    = (const int*)d_in[8];
    const int* batch_categ   = (const int*)d_in[9];
    const float* Wp_central = (const float*)d_in[11];
    const float* bp_central = (const float*)d_in[12];
    const float* Wp_cont    = (const float*)d_in[13];
    const float* bp_cont    = (const float*)d_in[14];
    const float* Wp_categ   = (const float*)d_in[15];
    const float* bp_categ   = (const float*)d_in[16];
    const float* W_msg  = (const float*)d_in[17];
    const float* b_msg  = (const float*)d_in[18];
    const float* W_root = (const float*)d_in[19];
    const float* Wg     = (const float*)d_in[20];
    const float* bg     = (const float*)d_in[21];
    float* out = (float*)d_out;

    char* base = (char*)d_ws;
    size_t off = 0;
    auto alloc = [&](size_t bytes) -> void* {
        off = (off + 255) & ~(size_t)255;
        void* p = base + off; off += bytes; return p;
    };

    unsigned short* hc   = (unsigned short*)alloc((size_t)NCn * Hh * 2);
    unsigned short* h1   = (unsigned short*)alloc((size_t)N1n * Hh * 2);
    unsigned short* h2   = (unsigned short*)alloc((size_t)N2n * Hh * 2);
    unsigned short* t    = (unsigned short*)alloc((size_t)NCn * 512 * 2);
    unsigned short* cat  = (unsigned short*)alloc((size_t)NCn * 768 * 2);
    unsigned short* agg0 = (unsigned short*)alloc((size_t)N1n * Hh * 2);
    unsigned short* agg2 = (unsigned short*)alloc((size_t)N2n * Hh * 2);

    unsigned short* Wt8  = (unsigned short*)alloc((size_t)8 * 65536 * 2);
    unsigned short* Wtc  = (unsigned short*)alloc((size_t)2 * 196608 * 2);
    float* b_central     = (float*)alloc(512 * 4);

    const int nd[4] = { N1n, NCn, N2n, NCn };
    int* rp[4]; int* cs[4];
    for (int r = 0; r < 4; ++r) {
        rp[r] = (int*)alloc((size_t)(nd[r] + 1) * 4);
        cs[r] = (int*)alloc((size_t)En * 4);
    }
    int* deg_fill = (int*)alloc((size_t)320000 * 4);   // [0,160000) deg, [160000,320000) fill
    int* partials = (int*)alloc(256 * 4);
    int* bounds   = (int*)alloc((size_t)3 * (Bn + 1) * 4);
    (void)ws_size; (void)in_sizes; (void)n_in; (void)out_size;

    // --- weight prep (2 dispatches) ---
    wt8_prep<<<2048, 256, 0, stream>>>(W_msg, W_root, Wt8);
    wtcat_prep<<<1538, 256, 0, stream>>>(W_msg, W_root, b_msg, Wtc, b_central);

    // --- input projections (2 dispatches) ---
    proj_kernel<64><<<NCn, 256, 0, stream>>>(x_central, Wp_central, bp_central, hc);
    proj_child<<<N1n + N2n, 256, 0, stream>>>(x_cont, Wp_cont, bp_cont, h1,
                                              x_categ, Wp_categ, bp_categ, h2);

    // --- CSR build (6 dispatches) ---
    CPtr4 srcs = {{ ei_c2cont, ei_cont2c, ei_c2categ, ei_categ2c }};
    CPtr4 dsts = {{ ei_c2cont + En, ei_cont2c + En, ei_c2categ + En, ei_categ2c + En }};
    IPtr4 rps  = {{ rp[0], rp[1], rp[2], rp[3] }};
    CPtr4 rpc  = {{ rp[0], rp[1], rp[2], rp[3] }};
    IPtr4 css  = {{ cs[0], cs[1], cs[2], cs[3] }};
    zero_i32<<<1250, 256, 0, stream>>>(deg_fill, 320000);
    deg_count_all<<<3125, 256, 0, stream>>>(dsts, deg_fill);
    scan_chunk_all<<<158, 1024, 0, stream>>>(deg_fill, rps, partials);
    scan_partials_all<<<4, 64, 0, stream>>>(partials);
    scan_add_all<<<158, 1024, 0, stream>>>(rps, partials);
    scatter_all<<<3125, 256, 0, stream>>>(srcs, dsts, rpc, deg_fill + 160000, css);

    // --- GNN layers (5 dispatches each) ---
    for (int l = 0; l < 2; ++l) {
        const unsigned short* Wt_msg_all = Wt8 + (size_t)(l * 4 + 0) * 65536;  // [512][256]
        const unsigned short* Wt_root0   = Wt8 + (size_t)(l * 4 + 2) * 65536;
        const unsigned short* Wt_root2   = Wt8 + (size_t)(l * 4 + 3) * 65536;
        const unsigned short* Wt_cat     = Wtc + (size_t)l * 196608;

        // msg transform on small side: t[NC][512] = hc @ [Wm0 | Wm2]
        gemm_dir<8, false, false><<<dim3(NCn / 32, 2), 256, 0, stream>>>(
            hc, Hh, Wt_msg_all, nullptr, nullptr, 0, t, 512, NCn);

        // aggs into cat (h1->cat[:,0:256], h2->cat[:,256:512], hc copy->cat[:,512:768])
        AggDesc ca0 = { h1, rp[1], cs[1], cat, Hh, 768, 0,   NCn };
        AggDesc ca1 = { h2, rp[3], cs[3], cat, Hh, 768, 256, NCn };
        AggDesc ca2 = { hc, nullptr, nullptr, cat, Hh, 768, 512, NCn };
        agg_all<<<dim3(NCn / 4, 3), 256, 0, stream>>>(ca0, ca1, ca2);

        // aggs to children from t (t0 = cols 0:256, t2 = cols 256:512)
        AggDesc ch0 = { t,       rp[0], cs[0], agg0, 512, Hh, 0, N1n };
        AggDesc ch1 = { t + 256, rp[2], cs[2], agg2, 512, Hh, 0, N2n };
        agg_all<<<dim3(N1n / 4, 2), 256, 0, stream>>>(ch0, ch1, ch0);

        GemmDesc g0 = { h1, Wt_root0, b_msg + (size_t)(l * 4 + 0) * Hh, agg0, h1 };
        GemmDesc g1 = { h2, Wt_root2, b_msg + (size_t)(l * 4 + 2) * Hh, agg2, h2 };
        if (l == 0) {
            gemm_dir<24, true, false><<<dim3(NCn / 32, 1), 256, 0, stream>>>(
                cat, 768, Wt_cat, b_central + l * 256, nullptr, 0, hc, Hh, NCn);
            gemm_pair<8, true, true><<<dim3(N1n / 32, 2), 256, 0, stream>>>(
                g0, g1, Hh, Hh, Hh, N1n);
        } else {
            gemm_dir<24, false, false><<<dim3(NCn / 32, 1), 256, 0, stream>>>(
                cat, 768, Wt_cat, b_central + l * 256, nullptr, 0, hc, Hh, NCn);
            gemm_pair<8, false, true><<<dim3(N1n / 32, 2), 256, 0, stream>>>(
                g0, g1, Hh, Hh, Hh, N1n);
        }
    }

    // --- pooling + final (2 dispatches) ---
    graph_bounds_all<<<7, 256, 0, stream>>>(batch_central, batch_cont, batch_categ, bounds);
    pool_final<<<Bn, 256, 0, stream>>>(hc, h1, h2, bounds, Wg, bg, out);
}

// Round 4
// 408.366 us; speedup vs baseline: 2.7521x; 2.0715x over previous
//
#include <hip/hip_runtime.h>

#define Hh   256
#define NCn  20000
#define N1n  60000
#define N2n  60000
#define En   200000
#define Bn   512
#define OUTn 128
#define KA   96        // layer-0 packed-A stride / GEMM K
#define PGW  1792      // per-graph concat width (7 x 256)

using bf16x8 = __attribute__((ext_vector_type(8))) __bf16;
using f32x4  = __attribute__((ext_vector_type(4))) float;

__device__ __forceinline__ float bf2f(unsigned short u) {
    union { unsigned int i; float f; } v; v.i = ((unsigned int)u) << 16; return v.f;
}
__device__ __forceinline__ unsigned short f2bf(float f) {
    union { float f; unsigned int i; } v; v.f = f;
    unsigned int r = v.i + 0x7FFFu + ((v.i >> 16) & 1u);
    return (unsigned short)(r >> 16);
}
__device__ __forceinline__ float bflo(unsigned int u) {
    union { unsigned int i; float f; } v; v.i = u << 16; return v.f;
}
__device__ __forceinline__ float bfhi(unsigned int u) {
    union { unsigned int i; float f; } v; v.i = u & 0xffff0000u; return v.f;
}
__device__ __forceinline__ int imax(int a, int b) { return a > b ? a : b; }

struct CPtr4 { const int* p[4]; };
struct IPtr4 { int* p[4]; };

// ---------------- input packing: raw features -> bf16 A-panels -------------------------
// A0[NC][96]: cols 0:64 = bf16(x_central); cols 64:96 filled by raw_agg
// A1[N1][96]: cols 64:80 = bf16(x_cont), 80:96 = 0; cols 0:64 by raw_agg
// A2[N2][96]: same with x_categ
__global__ void pack_inputs(const float* __restrict__ xc, const float* __restrict__ x1,
                            const float* __restrict__ x2, unsigned short* __restrict__ A0,
                            unsigned short* __restrict__ A1, unsigned short* __restrict__ A2) {
    int idx = blockIdx.x * 256 + threadIdx.x;
    const int c0 = NCn * 64, c1 = c0 + N1n * 32, c2 = c1 + N2n * 32;
    if (idx < c0) {
        int m = idx >> 6, c = idx & 63;
        A0[(size_t)m * KA + c] = f2bf(xc[(size_t)m * 64 + c]);
    } else if (idx < c1) {
        int i = idx - c0; int m = i >> 5, c = i & 31;
        A1[(size_t)m * KA + 64 + c] = (c < 16) ? f2bf(x1[(size_t)m * 16 + c]) : (unsigned short)0;
    } else if (idx < c2) {
        int i = idx - c1; int m = i >> 5, c = i & 31;
        A2[(size_t)m * KA + 64 + c] = (c < 16) ? f2bf(x2[(size_t)m * 16 + c]) : (unsigned short)0;
    }
}

// ---------------- CSR build (relation-batched; unchanged from R2) ----------------------
__device__ __forceinline__ int degoff_of(int rel) {
    const int t[4] = { 0, N1n, N1n + NCn, N1n + NCn + N2n };
    return t[rel];
}
__device__ __forceinline__ int nrel_of(int rel) {
    const int t[4] = { N1n, NCn, N2n, NCn };
    return t[rel];
}
__device__ __forceinline__ void rel_chunk(int b, int& rel, int& c) {
    if (b < 59)       { rel = 0; c = b; }
    else if (b < 79)  { rel = 1; c = b - 59; }
    else if (b < 138) { rel = 2; c = b - 79; }
    else              { rel = 3; c = b - 138; }
}
__global__ void zero_i32(int* p, int n) {
    int i = blockIdx.x * 256 + threadIdx.x; if (i < n) p[i] = 0;
}
__global__ void deg_count_all(CPtr4 dst, int* __restrict__ deg_all) {
    int i = blockIdx.x * 256 + threadIdx.x;
    if (i >= 4 * En) return;
    int rel = i / En; int e = i - rel * En;
    atomicAdd(&deg_all[degoff_of(rel) + dst.p[rel][e]], 1);
}
__global__ void __launch_bounds__(1024) scan_chunk_all(const int* __restrict__ deg_all,
                                                       IPtr4 rp, int* __restrict__ partials) {
    int rel, c; rel_chunk(blockIdx.x, rel, c);
    int n = nrel_of(rel);
    __shared__ int sh[1024];
    int tid = threadIdx.x;
    int i = c * 1024 + tid;
    int v = (i < n) ? deg_all[degoff_of(rel) + i] : 0;
    sh[tid] = v; __syncthreads();
    for (int off = 1; off < 1024; off <<= 1) {
        int t = (tid >= off) ? sh[tid - off] : 0; __syncthreads();
        sh[tid] += t; __syncthreads();
    }
    if (i < n) rp.p[rel][i] = sh[tid] - v;
    if (tid == 1023) partials[rel * 64 + c] = sh[1023];
}
__global__ void scan_partials_all(int* partials) {
    const int nch[4] = { 59, 20, 59, 20 };
    int rel = blockIdx.x;
    __shared__ int sh[64];
    int tid = threadIdx.x;
    int v = (tid < nch[rel]) ? partials[rel * 64 + tid] : 0;
    sh[tid] = v; __syncthreads();
    for (int off = 1; off < 64; off <<= 1) {
        int t = (tid >= off) ? sh[tid - off] : 0; __syncthreads();
        sh[tid] += t; __syncthreads();
    }
    if (tid < nch[rel]) partials[rel * 64 + tid] = sh[tid] - v;
}
__global__ void __launch_bounds__(1024) scan_add_all(IPtr4 rp, const int* __restrict__ partials) {
    int rel, c; rel_chunk(blockIdx.x, rel, c);
    int n = nrel_of(rel);
    int tid = threadIdx.x;
    int i = c * 1024 + tid;
    if (i < n) rp.p[rel][i] += partials[rel * 64 + c];
    if (c == 0 && tid == 0) rp.p[rel][n] = En;
}
__global__ void scatter_all(CPtr4 src, CPtr4 dst, CPtr4 rp, int* fill_all, IPtr4 cs) {
    int i = blockIdx.x * 256 + threadIdx.x;
    if (i >= 4 * En) return;
    int rel = i / En; int e = i - rel * En;
    int d = dst.p[rel][e];
    int pos = rp.p[rel][d] + atomicAdd(&fill_all[degoff_of(rel) + d], 1);
    cs.p[rel][pos] = src.p[rel][e];
}

// ---------------- raw-feature segment mean (layer 0) -----------------------------------
struct RawDesc {
    const unsigned short* feat;   // stride 96
    const int* rowptr;
    const int* colsrc;
    unsigned short* out;          // stride 96
    int sh;                       // log2(col-groups of 4): 2 (16 cols) or 4 (64 cols)
    int n_dst;
    int ocol;
};
__global__ void raw_agg(RawDesc d0, RawDesc d1, RawDesc d2, RawDesc d3) {
    RawDesc d = (blockIdx.y == 0) ? d0 : (blockIdx.y == 1) ? d1 : (blockIdx.y == 2) ? d2 : d3;
    int idx = blockIdx.x * 256 + threadIdx.x;
    int node = idx >> d.sh;
    int c4 = idx & ((1 << d.sh) - 1);
    if (node >= d.n_dst) return;
    int s = d.rowptr[node], e = d.rowptr[node + 1];
    float a0 = 0.f, a1 = 0.f, a2 = 0.f, a3 = 0.f;
    for (int i = s; i < e; ++i) {
        int sc = d.colsrc[i];
        ushort4 v = *reinterpret_cast<const ushort4*>(d.feat + (size_t)sc * KA + c4 * 4);
        a0 += bf2f(v.x); a1 += bf2f(v.y); a2 += bf2f(v.z); a3 += bf2f(v.w);
    }
    float inv = 1.0f / (float)imax(e - s, 1);
    ushort4 o;
    o.x = f2bf(a0 * inv); o.y = f2bf(a1 * inv); o.z = f2bf(a2 * inv); o.w = f2bf(a3 * inv);
    *reinterpret_cast<ushort4*>(d.out + (size_t)node * KA + d.ocol + c4 * 4) = o;
}

// ---------------- layer-0 weight folding ------------------------------------------------
// Wt3[mat][n*96+k] (transposed bf16), mat 0=central, 1=child_cont, 2=child_categ
// central:  k<64: Wpc @ 0.5(Wr1+Wr3);  64:80: Wp1 @ 0.5Wm1;  80:96: Wp2 @ 0.5Wm3
// child1:   k<64: Wpc @ Wm0;           64:80: Wp1 @ Wr0;     80:96: 0
// child2:   k<64: Wpc @ Wm2;           64:80: Wp2 @ Wr2;     80:96: 0
__global__ void wfold(const float* __restrict__ Wm, const float* __restrict__ Wr,
                      const float* __restrict__ Wpc, const float* __restrict__ Wp1,
                      const float* __restrict__ Wp2, unsigned short* __restrict__ Wt3) {
    __shared__ float cA[256], cB[256], cC[256];
    int n = blockIdx.x, mat = blockIdx.y, tid = threadIdx.x;
    for (int j = tid; j < 256; j += 128) {
        if (mat == 0) {
            cA[j] = 0.5f * (Wr[1 * 65536 + j * 256 + n] + Wr[3 * 65536 + j * 256 + n]);
            cB[j] = 0.5f * Wm[1 * 65536 + j * 256 + n];
            cC[j] = 0.5f * Wm[3 * 65536 + j * 256 + n];
        } else if (mat == 1) {
            cA[j] = Wm[0 * 65536 + j * 256 + n];
            cB[j] = Wr[0 * 65536 + j * 256 + n];
            cC[j] = 0.f;
        } else {
            cA[j] = Wm[2 * 65536 + j * 256 + n];
            cB[j] = Wr[2 * 65536 + j * 256 + n];
            cC[j] = 0.f;
        }
    }
    __syncthreads();
    int k = tid;
    if (k >= KA) return;
    float w = 0.f;
    if (k < 64) {
        for (int j = 0; j < 256; ++j) w = fmaf(Wpc[k * 256 + j], cA[j], w);
    } else if (k < 80) {
        const float* Wp = (mat == 2) ? Wp2 : Wp1;
        for (int j = 0; j < 256; ++j) w = fmaf(Wp[(k - 64) * 256 + j], cB[j], w);
    } else if (mat == 0) {
        for (int j = 0; j < 256; ++j) w = fmaf(Wp2[(k - 80) * 256 + j], cC[j], w);
    }
    Wt3[(size_t)mat * 256 * KA + n * KA + k] = f2bf(w);
}

__global__ void bias_fold(const float* __restrict__ Wm, const float* __restrict__ Wr,
                          const float* __restrict__ bm, const float* __restrict__ bpc,
                          const float* __restrict__ bp1, const float* __restrict__ bp2,
                          float* __restrict__ bC, float* __restrict__ bB1, float* __restrict__ bB2) {
    int n = blockIdx.x * 128 + threadIdx.x;
    if (n >= 256) return;
    float s0 = 0, s1 = 0, s2 = 0, t0 = 0, t1 = 0, u0 = 0, u1 = 0;
    for (int j = 0; j < 256; ++j) {
        float wr1 = Wr[1 * 65536 + j * 256 + n], wr3 = Wr[3 * 65536 + j * 256 + n];
        float wm1 = Wm[1 * 65536 + j * 256 + n], wm3 = Wm[3 * 65536 + j * 256 + n];
        float wm0 = Wm[0 * 65536 + j * 256 + n], wr0 = Wr[0 * 65536 + j * 256 + n];
        float wm2 = Wm[2 * 65536 + j * 256 + n], wr2 = Wr[2 * 65536 + j * 256 + n];
        float bc = bpc[j], b1 = bp1[j], b2 = bp2[j];
        s0 = fmaf(bc, 0.5f * (wr1 + wr3), s0);
        s1 = fmaf(b1, 0.5f * wm1, s1);
        s2 = fmaf(b2, 0.5f * wm3, s2);
        t0 = fmaf(bc, wm0, t0); t1 = fmaf(b1, wr0, t1);
        u0 = fmaf(bc, wm2, u0); u1 = fmaf(b2, wr2, u1);
    }
    bC[n]  = s0 + s1 + s2 + 0.5f * (bm[1 * 256 + n] + bm[3 * 256 + n]);
    bB1[n] = t0 + t1 + bm[0 * 256 + n];
    bB2[n] = u0 + u1 + bm[2 * 256 + n];
}

// layer-1 stacked per-graph weight [256][1792] transposed bf16 (x 1/3), + bias
__global__ void wpg_prep(const float* __restrict__ Wm, const float* __restrict__ Wr,
                         const float* __restrict__ bm, unsigned short* __restrict__ WPGt,
                         float* __restrict__ bPG) {
    int idx = blockIdx.x * 256 + threadIdx.x;
    const float third = 1.0f / 3.0f;
    if (idx < 256 * PGW) {
        int n = idx / PGW, k = idx - n * PGW;
        int blk = k >> 8, kk = k & 255;
        float v;
        switch (blk) {
            case 0:  v = 0.5f * Wm[1 * 65536 + kk * 256 + n]; break;
            case 1:  v = 0.5f * Wm[3 * 65536 + kk * 256 + n]; break;
            case 2:  v = 0.5f * (Wr[1 * 65536 + kk * 256 + n] + Wr[3 * 65536 + kk * 256 + n]); break;
            case 3:  v = Wm[0 * 65536 + kk * 256 + n]; break;
            case 4:  v = Wr[0 * 65536 + kk * 256 + n]; break;
            case 5:  v = Wm[2 * 65536 + kk * 256 + n]; break;
            default: v = Wr[2 * 65536 + kk * 256 + n]; break;
        }
        WPGt[idx] = f2bf(v * third);
    } else if (idx < 256 * PGW + 256) {
        int n = idx - 256 * PGW;
        bPG[n] = third * (0.5f * (bm[1 * 256 + n] + bm[3 * 256 + n]) + bm[0 * 256 + n] + bm[2 * 256 + n]);
    }
}

// ---------------- layer-0 GEMM: K=96, N=256, bias+relu, 3 fused instances --------------
struct G96 {
    const unsigned short* A;   // [M][96]
    const unsigned short* Wt;  // [256][96] transposed
    const float* bias;
    unsigned short* C;         // [M][256]
    int M;
};
__global__ void __launch_bounds__(256) gemm96(G96 g0, G96 g1, G96 g2) {
    G96 g = (blockIdx.y == 0) ? g0 : (blockIdx.y == 1) ? g1 : g2;
    const int m0 = blockIdx.x * 32;
    if (m0 >= g.M) return;
    const int tid = threadIdx.x;
    const int wid = tid >> 6, lane = tid & 63;
    const int llo = lane & 15, lhi = lane >> 4;
    const int cb = wid * 64;

    const unsigned short* pA[2];
#pragma unroll
    for (int rt = 0; rt < 2; ++rt)
        pA[rt] = g.A + (size_t)(m0 + rt * 16 + llo) * KA + lhi * 8;
    const unsigned short* pB[4];
#pragma unroll
    for (int ct = 0; ct < 4; ++ct)
        pB[ct] = g.Wt + (size_t)(cb + ct * 16 + llo) * KA + lhi * 8;

    f32x4 acc[2][4] = {};
    bf16x8 a0[2], a1[2], a2[2], b0[4], b1[4], b2[4];
#pragma unroll
    for (int t = 0; t < 2; ++t) {
        a0[t] = *reinterpret_cast<const bf16x8*>(pA[t]);
        a1[t] = *reinterpret_cast<const bf16x8*>(pA[t] + 32);
        a2[t] = *reinterpret_cast<const bf16x8*>(pA[t] + 64);
    }
#pragma unroll
    for (int t = 0; t < 4; ++t) {
        b0[t] = *reinterpret_cast<const bf16x8*>(pB[t]);
        b1[t] = *reinterpret_cast<const bf16x8*>(pB[t] + 32);
        b2[t] = *reinterpret_cast<const bf16x8*>(pB[t] + 64);
    }
#pragma unroll
    for (int rt = 0; rt < 2; ++rt)
#pragma unroll
        for (int ct = 0; ct < 4; ++ct) {
            acc[rt][ct] = __builtin_amdgcn_mfma_f32_16x16x32_bf16(b0[ct], a0[rt], acc[rt][ct], 0, 0, 0);
            acc[rt][ct] = __builtin_amdgcn_mfma_f32_16x16x32_bf16(b1[ct], a1[rt], acc[rt][ct], 0, 0, 0);
            acc[rt][ct] = __builtin_amdgcn_mfma_f32_16x16x32_bf16(b2[ct], a2[rt], acc[rt][ct], 0, 0, 0);
        }

#pragma unroll
    for (int rt = 0; rt < 2; ++rt) {
        const int row = m0 + rt * 16 + llo;
#pragma unroll
        for (int ct = 0; ct < 4; ++ct) {
            const int col0 = cb + ct * 16 + lhi * 4;
            float4 bv = *reinterpret_cast<const float4*>(g.bias + col0);
            float v0 = fmaxf(acc[rt][ct][0] + bv.x, 0.f);
            float v1 = fmaxf(acc[rt][ct][1] + bv.y, 0.f);
            float v2 = fmaxf(acc[rt][ct][2] + bv.z, 0.f);
            float v3 = fmaxf(acc[rt][ct][3] + bv.w, 0.f);
            ushort4 o;
            o.x = f2bf(v0); o.y = f2bf(v1); o.z = f2bf(v2); o.w = f2bf(v3);
            *reinterpret_cast<ushort4*>(g.C + (size_t)row * Hh + col0) = o;
        }
    }
}

// ---------------- per-graph aggregation (layer 1 collapsed) ----------------------------
struct PGDesc {
    const unsigned short* feat;   // [*][256]
    const int* bound;             // 513 entries
    const int* rowptr;            // nullptr => plain segment mean over nodes
    const int* colsrc;
    int ocol;
};
struct PGAll { PGDesc d[7]; };
__global__ void __launch_bounds__(256) pg_agg(PGAll all, unsigned short* __restrict__ PG) {
    PGDesc d = all.d[blockIdx.y];
    int g = blockIdx.x;
    int s = d.bound[g], e = d.bound[g + 1];
    int tid = threadIdx.x, wid = tid >> 6, lane = tid & 63;
    float a0 = 0.f, a1 = 0.f, a2 = 0.f, a3 = 0.f;
    if (d.rowptr) {
        for (int n = s + wid; n < e; n += 4) {
            int rs = d.rowptr[n], re = d.rowptr[n + 1];
            float w = 1.0f / (float)imax(re - rs, 1);
            float b0 = 0.f, b1 = 0.f, b2 = 0.f, b3 = 0.f;
            for (int i = rs; i < re; ++i) {
                int sc = d.colsrc[i];
                ushort4 v = *reinterpret_cast<const ushort4*>(d.feat + (size_t)sc * Hh + lane * 4);
                b0 += bf2f(v.x); b1 += bf2f(v.y); b2 += bf2f(v.z); b3 += bf2f(v.w);
            }
            a0 = fmaf(b0, w, a0); a1 = fmaf(b1, w, a1);
            a2 = fmaf(b2, w, a2); a3 = fmaf(b3, w, a3);
        }
    } else {
        for (int n = s + wid; n < e; n += 4) {
            ushort4 v = *reinterpret_cast<const ushort4*>(d.feat + (size_t)n * Hh + lane * 4);
            a0 += bf2f(v.x); a1 += bf2f(v.y); a2 += bf2f(v.z); a3 += bf2f(v.w);
        }
    }
    __shared__ float sh[4][256];
    sh[wid][lane * 4 + 0] = a0; sh[wid][lane * 4 + 1] = a1;
    sh[wid][lane * 4 + 2] = a2; sh[wid][lane * 4 + 3] = a3;
    __syncthreads();
    float r = sh[0][tid] + sh[1][tid] + sh[2][tid] + sh[3][tid];
    r *= 1.0f / (float)imax(e - s, 1);
    PG[(size_t)g * PGW + d.ocol + tid] = f2bf(r);
}

// ---------------- per-graph GEMM + final linear -----------------------------------------
__global__ void graph_bounds_all(const int* __restrict__ bc, const int* __restrict__ b1,
                                 const int* __restrict__ b2, int* __restrict__ bound) {
    int idx = blockIdx.x * 256 + threadIdx.x;
    if (idx >= 3 * (Bn + 1)) return;
    int t = idx / (Bn + 1); int b = idx - t * (Bn + 1);
    const int* batch = (t == 0) ? bc : (t == 1) ? b1 : b2;
    int n = (t == 0) ? NCn : (t == 1) ? N1n : N2n;
    int lo = 0, hi = n;
    while (lo < hi) { int mid = (lo + hi) >> 1; if (batch[mid] < b) lo = mid + 1; else hi = mid; }
    bound[idx] = lo;
}
__global__ void __launch_bounds__(256) emb_final(const unsigned short* __restrict__ PG,
                                                 const unsigned short* __restrict__ WPGt,
                                                 const float* __restrict__ bPG,
                                                 const float* __restrict__ Wg,
                                                 const float* __restrict__ bg,
                                                 float* __restrict__ out) {
    __shared__ unsigned short arow[PGW];
    __shared__ float emb[256];
    int g = blockIdx.x, tid = threadIdx.x;
    if (tid < PGW / 8)
        reinterpret_cast<uint4*>(arow)[tid] =
            reinterpret_cast<const uint4*>(PG + (size_t)g * PGW)[tid];
    __syncthreads();
    float acc = bPG[tid];
    const unsigned short* wrow = WPGt + (size_t)tid * PGW;
    for (int k8 = 0; k8 < PGW / 8; ++k8) {
        uint4 av = *reinterpret_cast<const uint4*>(arow + k8 * 8);
        uint4 wv = *reinterpret_cast<const uint4*>(wrow + k8 * 8);
        acc = fmaf(bflo(av.x), bflo(wv.x), acc);
        acc = fmaf(bfhi(av.x), bfhi(wv.x), acc);
        acc = fmaf(bflo(av.y), bflo(wv.y), acc);
        acc = fmaf(bfhi(av.y), bfhi(wv.y), acc);
        acc = fmaf(bflo(av.z), bflo(wv.z), acc);
        acc = fmaf(bfhi(av.z), bfhi(wv.z), acc);
        acc = fmaf(bflo(av.w), bflo(wv.w), acc);
        acc = fmaf(bfhi(av.w), bfhi(wv.w), acc);
    }
    emb[tid] = acc;
    __syncthreads();
    if (tid < OUTn) {
        float o = bg[tid];
#pragma unroll 8
        for (int k = 0; k < 256; ++k) o = fmaf(emb[k], Wg[k * OUTn + tid], o);
        out[(size_t)g * OUTn + tid] = o;
    }
}

// ---------------- host orchestration ----------------------------------------------------
extern "C" void kernel_launch(void* const* d_in, const int* in_sizes, int n_in,
                              void* d_out, int out_size, void* d_ws, size_t ws_size,
                              hipStream_t stream) {
    const float* x_central = (const float*)d_in[0];
    const float* x_cont    = (const float*)d_in[1];
    const float* x_categ   = (const float*)d_in[2];
    const int* ei_c2cont   = (const int*)d_in[3];
    const int* ei_cont2c   = (const int*)d_in[4];
    const int* ei_c2categ  = (const int*)d_in[5];
    const int* ei_categ2c  = (const int*)d_in[6];
    const int* batch_central = (const int*)d_in[7];
    const int* batch_cont    = (const int*)d_in[8];
    const int* batch_categ   = (const int*)d_in[9];
    const float* Wp_central = (const float*)d_in[11];
    const float* bp_central = (const float*)d_in[12];
    const float* Wp_cont    = (const float*)d_in[13];
    const float* bp_cont    = (const float*)d_in[14];
    const float* Wp_categ   = (const float*)d_in[15];
    const float* bp_categ   = (const float*)d_in[16];
    const float* W_msg  = (const float*)d_in[17];
    const float* b_msg  = (const float*)d_in[18];
    const float* W_root = (const float*)d_in[19];
    const float* Wg     = (const float*)d_in[20];
    const float* bg     = (const float*)d_in[21];
    float* out = (float*)d_out;

    char* base = (char*)d_ws;
    size_t off = 0;
    auto alloc = [&](size_t bytes) -> void* {
        off = (off + 255) & ~(size_t)255;
        void* p = base + off; off += bytes; return p;
    };

    unsigned short* A0  = (unsigned short*)alloc((size_t)NCn * KA * 2);
    unsigned short* A1  = (unsigned short*)alloc((size_t)N1n * KA * 2);
    unsigned short* A2  = (unsigned short*)alloc((size_t)N2n * KA * 2);
    unsigned short* hc1 = (unsigned short*)alloc((size_t)NCn * Hh * 2);
    unsigned short* h11 = (unsigned short*)alloc((size_t)N1n * Hh * 2);
    unsigned short* h21 = (unsigned short*)alloc((size_t)N2n * Hh * 2);
    unsigned short* PG  = (unsigned short*)alloc((size_t)Bn * PGW * 2);

    unsigned short* Wt3  = (unsigned short*)alloc((size_t)3 * 256 * KA * 2);
    unsigned short* WPGt = (unsigned short*)alloc((size_t)256 * PGW * 2);
    float* bC  = (float*)alloc(256 * 4);
    float* bB1 = (float*)alloc(256 * 4);
    float* bB2 = (float*)alloc(256 * 4);
    float* bPG = (float*)alloc(256 * 4);

    const int nd[4] = { N1n, NCn, N2n, NCn };
    int* rp[4]; int* cs[4];
    for (int r = 0; r < 4; ++r) {
        rp[r] = (int*)alloc((size_t)(nd[r] + 1) * 4);
        cs[r] = (int*)alloc((size_t)En * 4);
    }
    int* deg_fill = (int*)alloc((size_t)320000 * 4);
    int* partials = (int*)alloc(256 * 4);
    int* bounds   = (int*)alloc((size_t)3 * (Bn + 1) * 4);
    (void)ws_size; (void)in_sizes; (void)n_in; (void)out_size;

    const float* Wm0 = W_msg;                       // layer 0 (4 x 256 x 256)
    const float* Wr0 = W_root;
    const float* Wm1 = W_msg  + (size_t)4 * 65536;  // layer 1
    const float* Wr1 = W_root + (size_t)4 * 65536;
    const float* bm0 = b_msg;
    const float* bm1 = b_msg + 4 * 256;

    // --- packing + weight prep ---
    pack_inputs<<<20000, 256, 0, stream>>>(x_central, x_cont, x_categ, A0, A1, A2);
    wfold<<<dim3(256, 3), 128, 0, stream>>>(Wm0, Wr0, Wp_central, Wp_cont, Wp_categ, Wt3);
    bias_fold<<<2, 128, 0, stream>>>(Wm0, Wr0, bm0, bp_central, bp_cont, bp_categ, bC, bB1, bB2);
    wpg_prep<<<1793, 256, 0, stream>>>(Wm1, Wr1, bm1, WPGt, bPG);
    graph_bounds_all<<<7, 256, 0, stream>>>(batch_central, batch_cont, batch_categ, bounds);

    // --- CSR build ---
    CPtr4 srcs = {{ ei_c2cont, ei_cont2c, ei_c2categ, ei_categ2c }};
    CPtr4 dsts = {{ ei_c2cont + En, ei_cont2c + En, ei_c2categ + En, ei_categ2c + En }};
    IPtr4 rps  = {{ rp[0], rp[1], rp[2], rp[3] }};
    CPtr4 rpc  = {{ rp[0], rp[1], rp[2], rp[3] }};
    IPtr4 css  = {{ cs[0], cs[1], cs[2], cs[3] }};
    zero_i32<<<1250, 256, 0, stream>>>(deg_fill, 320000);
    deg_count_all<<<3125, 256, 0, stream>>>(dsts, deg_fill);
    scan_chunk_all<<<158, 1024, 0, stream>>>(deg_fill, rps, partials);
    scan_partials_all<<<4, 64, 0, stream>>>(partials);
    scan_add_all<<<158, 1024, 0, stream>>>(rps, partials);
    scatter_all<<<3125, 256, 0, stream>>>(srcs, dsts, rpc, deg_fill + 160000, css);

    // --- layer-0 raw aggregations (into A panels) ---
    RawDesc r0 = { A1 + 64, rp[1], cs[1], A0, 2, NCn, 64 };   // cont  -> central (16 cols)
    RawDesc r1 = { A2 + 64, rp[3], cs[3], A0, 2, NCn, 80 };   // categ -> central
    RawDesc r2 = { A0,      rp[0], cs[0], A1, 4, N1n, 0 };    // central -> cont (64 cols)
    RawDesc r3 = { A0,      rp[2], cs[2], A2, 4, N2n, 0 };    // central -> categ
    raw_agg<<<dim3(3750, 4), 256, 0, stream>>>(r0, r1, r2, r3);

    // --- layer-0 GEMMs (K=96, bias+relu) ---
    G96 gc = { A0, Wt3,                 bC,  hc1, NCn };
    G96 g1 = { A1, Wt3 + 1 * 256 * KA,  bB1, h11, N1n };
    G96 g2 = { A2, Wt3 + 2 * 256 * KA,  bB2, h21, N2n };
    gemm96<<<dim3(1875, 3), 256, 0, stream>>>(g1, g2, gc);

    // --- layer-1 collapsed to per-graph aggregation ---
    PGAll pa;
    pa.d[0] = { h11, bounds,                rp[1], cs[1], 0 };
    pa.d[1] = { h21, bounds,                rp[3], cs[3], 256 };
    pa.d[2] = { hc1, bounds,                nullptr, nullptr, 512 };
    pa.d[3] = { hc1, bounds + (Bn + 1),     rp[0], cs[0], 768 };
    pa.d[4] = { h11, bounds + (Bn + 1),     nullptr, nullptr, 1024 };
    pa.d[5] = { hc1, bounds + 2 * (Bn + 1), rp[2], cs[2], 1280 };
    pa.d[6] = { h21, bounds + 2 * (Bn + 1), nullptr, nullptr, 1536 };
    pg_agg<<<dim3(Bn, 7), 256, 0, stream>>>(pa, PG);

    // --- final: emb = PG @ WPGt + bPG; out = emb @ Wg + bg ---
    emb_final<<<Bn, 256, 0, stream>>>(PG, WPGt, bPG, Wg, bg, out);
}

// Round 5
// 359.320 us; speedup vs baseline: 3.1277x; 1.1365x over previous
//
#include <hip/hip_runtime.h>

#define Hh   256
#define NCn  20000
#define N1n  60000
#define N2n  60000
#define En   200000
#define Bn   512
#define OUTn 128
#define KA   96        // layer-0 packed-A stride / GEMM K
#define PGW  1792      // per-graph concat width (7 x 256)

using bf16x8 = __attribute__((ext_vector_type(8))) __bf16;
using f32x4  = __attribute__((ext_vector_type(4))) float;

__device__ __forceinline__ float bf2f(unsigned short u) {
    union { unsigned int i; float f; } v; v.i = ((unsigned int)u) << 16; return v.f;
}
__device__ __forceinline__ unsigned short f2bf(float f) {
    union { float f; unsigned int i; } v; v.f = f;
    unsigned int r = v.i + 0x7FFFu + ((v.i >> 16) & 1u);
    return (unsigned short)(r >> 16);
}
__device__ __forceinline__ int imax(int a, int b) { return a > b ? a : b; }

struct CPtr4 { const int* p[4]; };
struct IPtr4 { int* p[4]; };
struct FPtr4 { float* p[4]; };

// ---------------- input packing: raw features -> bf16 A-panels -------------------------
__global__ void pack_inputs(const float* __restrict__ xc, const float* __restrict__ x1,
                            const float* __restrict__ x2, unsigned short* __restrict__ A0,
                            unsigned short* __restrict__ A1, unsigned short* __restrict__ A2) {
    int idx = blockIdx.x * 256 + threadIdx.x;
    const int c0 = NCn * 64, c1 = c0 + N1n * 32, c2 = c1 + N2n * 32;
    if (idx < c0) {
        int m = idx >> 6, c = idx & 63;
        A0[(size_t)m * KA + c] = f2bf(xc[(size_t)m * 64 + c]);
    } else if (idx < c1) {
        int i = idx - c0; int m = i >> 5, c = i & 31;
        A1[(size_t)m * KA + 64 + c] = (c < 16) ? f2bf(x1[(size_t)m * 16 + c]) : (unsigned short)0;
    } else if (idx < c2) {
        int i = idx - c1; int m = i >> 5, c = i & 31;
        A2[(size_t)m * KA + 64 + c] = (c < 16) ? f2bf(x2[(size_t)m * 16 + c]) : (unsigned short)0;
    }
}

// ---------------- CSR build (relation-batched) ------------------------------------------
__device__ __forceinline__ int degoff_of(int rel) {
    const int t[4] = { 0, N1n, N1n + NCn, N1n + NCn + N2n };
    return t[rel];
}
__device__ __forceinline__ int nrel_of(int rel) {
    const int t[4] = { N1n, NCn, N2n, NCn };
    return t[rel];
}
__device__ __forceinline__ void rel_chunk(int b, int& rel, int& c) {
    if (b < 59)       { rel = 0; c = b; }
    else if (b < 79)  { rel = 1; c = b - 59; }
    else if (b < 138) { rel = 2; c = b - 79; }
    else              { rel = 3; c = b - 138; }
}
__global__ void zero_i32(int* p, int n) {
    int i = blockIdx.x * 256 + threadIdx.x; if (i < n) p[i] = 0;
}
__global__ void deg_count_all(CPtr4 dst, int* __restrict__ deg_all) {
    int i = blockIdx.x * 256 + threadIdx.x;
    if (i >= 4 * En) return;
    int rel = i / En; int e = i - rel * En;
    atomicAdd(&deg_all[degoff_of(rel) + dst.p[rel][e]], 1);
}
__global__ void __launch_bounds__(1024) scan_chunk_all(const int* __restrict__ deg_all,
                                                       IPtr4 rp, int* __restrict__ partials) {
    int rel, c; rel_chunk(blockIdx.x, rel, c);
    int n = nrel_of(rel);
    __shared__ int sh[1024];
    int tid = threadIdx.x;
    int i = c * 1024 + tid;
    int v = (i < n) ? deg_all[degoff_of(rel) + i] : 0;
    sh[tid] = v; __syncthreads();
    for (int off = 1; off < 1024; off <<= 1) {
        int t = (tid >= off) ? sh[tid - off] : 0; __syncthreads();
        sh[tid] += t; __syncthreads();
    }
    if (i < n) rp.p[rel][i] = sh[tid] - v;
    if (tid == 1023) partials[rel * 64 + c] = sh[1023];
}
__global__ void scan_partials_all(int* partials) {
    const int nch[4] = { 59, 20, 59, 20 };
    int rel = blockIdx.x;
    __shared__ int sh[64];
    int tid = threadIdx.x;
    int v = (tid < nch[rel]) ? partials[rel * 64 + tid] : 0;
    sh[tid] = v; __syncthreads();
    for (int off = 1; off < 64; off <<= 1) {
        int t = (tid >= off) ? sh[tid - off] : 0; __syncthreads();
        sh[tid] += t; __syncthreads();
    }
    if (tid < nch[rel]) partials[rel * 64 + tid] = sh[tid] - v;
}
__global__ void __launch_bounds__(1024) scan_add_all(IPtr4 rp, const int* __restrict__ partials) {
    int rel, c; rel_chunk(blockIdx.x, rel, c);
    int n = nrel_of(rel);
    int tid = threadIdx.x;
    int i = c * 1024 + tid;
    if (i < n) rp.p[rel][i] += partials[rel * 64 + c];
    if (c == 0 && tid == 0) rp.p[rel][n] = En;
}
// scatter + per-edge weight (1/deg of dst) in CSR order
__global__ void scatter_all(CPtr4 src, CPtr4 dst, CPtr4 rp, int* fill_all, IPtr4 cs, FPtr4 we) {
    int i = blockIdx.x * 256 + threadIdx.x;
    if (i >= 4 * En) return;
    int rel = i / En; int e = i - rel * En;
    int d = dst.p[rel][e];
    int rbase = rp.p[rel][d];
    int deg = rp.p[rel][d + 1] - rbase;
    int pos = rbase + atomicAdd(&fill_all[degoff_of(rel) + d], 1);
    cs.p[rel][pos] = src.p[rel][e];
    we.p[rel][pos] = 1.0f / (float)imax(deg, 1);
}

// ---------------- raw-feature segment mean (layer 0), 2-way edge ILP -------------------
struct RawDesc {
    const unsigned short* feat;   // stride 96
    const int* rowptr;
    const int* colsrc;
    unsigned short* out;          // stride 96
    int sh;                       // log2(col-groups of 4)
    int n_dst;
    int ocol;
};
__global__ void raw_agg(RawDesc d0, RawDesc d1, RawDesc d2, RawDesc d3) {
    RawDesc d = (blockIdx.y == 0) ? d0 : (blockIdx.y == 1) ? d1 : (blockIdx.y == 2) ? d2 : d3;
    int idx = blockIdx.x * 256 + threadIdx.x;
    int node = idx >> d.sh;
    int c4 = idx & ((1 << d.sh) - 1);
    if (node >= d.n_dst) return;
    int s = d.rowptr[node], e = d.rowptr[node + 1];
    float a0 = 0.f, a1 = 0.f, a2 = 0.f, a3 = 0.f;
    float b0 = 0.f, b1 = 0.f, b2 = 0.f, b3 = 0.f;
    int i = s;
    for (; i + 1 < e; i += 2) {
        int sc1 = d.colsrc[i], sc2 = d.colsrc[i + 1];
        ushort4 v1 = *reinterpret_cast<const ushort4*>(d.feat + (size_t)sc1 * KA + c4 * 4);
        ushort4 v2 = *reinterpret_cast<const ushort4*>(d.feat + (size_t)sc2 * KA + c4 * 4);
        a0 += bf2f(v1.x); a1 += bf2f(v1.y); a2 += bf2f(v1.z); a3 += bf2f(v1.w);
        b0 += bf2f(v2.x); b1 += bf2f(v2.y); b2 += bf2f(v2.z); b3 += bf2f(v2.w);
    }
    if (i < e) {
        int sc1 = d.colsrc[i];
        ushort4 v1 = *reinterpret_cast<const ushort4*>(d.feat + (size_t)sc1 * KA + c4 * 4);
        a0 += bf2f(v1.x); a1 += bf2f(v1.y); a2 += bf2f(v1.z); a3 += bf2f(v1.w);
    }
    a0 += b0; a1 += b1; a2 += b2; a3 += b3;
    float inv = 1.0f / (float)imax(e - s, 1);
    ushort4 o;
    o.x = f2bf(a0 * inv); o.y = f2bf(a1 * inv); o.z = f2bf(a2 * inv); o.w = f2bf(a3 * inv);
    *reinterpret_cast<ushort4*>(d.out + (size_t)node * KA + d.ocol + c4 * 4) = o;
}

// ---------------- layer-0 weight folding (unchanged) ------------------------------------
__global__ void wfold(const float* __restrict__ Wm, const float* __restrict__ Wr,
                      const float* __restrict__ Wpc, const float* __restrict__ Wp1,
                      const float* __restrict__ Wp2, unsigned short* __restrict__ Wt3) {
    __shared__ float cA[256], cB[256], cC[256];
    int n = blockIdx.x, mat = blockIdx.y, tid = threadIdx.x;
    for (int j = tid; j < 256; j += 128) {
        if (mat == 0) {
            cA[j] = 0.5f * (Wr[1 * 65536 + j * 256 + n] + Wr[3 * 65536 + j * 256 + n]);
            cB[j] = 0.5f * Wm[1 * 65536 + j * 256 + n];
            cC[j] = 0.5f * Wm[3 * 65536 + j * 256 + n];
        } else if (mat == 1) {
            cA[j] = Wm[0 * 65536 + j * 256 + n];
            cB[j] = Wr[0 * 65536 + j * 256 + n];
            cC[j] = 0.f;
        } else {
            cA[j] = Wm[2 * 65536 + j * 256 + n];
            cB[j] = Wr[2 * 65536 + j * 256 + n];
            cC[j] = 0.f;
        }
    }
    __syncthreads();
    int k = tid;
    if (k >= KA) return;
    float w = 0.f;
    if (k < 64) {
        for (int j = 0; j < 256; ++j) w = fmaf(Wpc[k * 256 + j], cA[j], w);
    } else if (k < 80) {
        const float* Wp = (mat == 2) ? Wp2 : Wp1;
        for (int j = 0; j < 256; ++j) w = fmaf(Wp[(k - 64) * 256 + j], cB[j], w);
    } else if (mat == 0) {
        for (int j = 0; j < 256; ++j) w = fmaf(Wp2[(k - 80) * 256 + j], cC[j], w);
    }
    Wt3[(size_t)mat * 256 * KA + n * KA + k] = f2bf(w);
}

__global__ void bias_fold(const float* __restrict__ Wm, const float* __restrict__ Wr,
                          const float* __restrict__ bm, const float* __restrict__ bpc,
                          const float* __restrict__ bp1, const float* __restrict__ bp2,
                          float* __restrict__ bC, float* __restrict__ bB1, float* __restrict__ bB2) {
    int n = blockIdx.x * 128 + threadIdx.x;
    if (n >= 256) return;
    float s0 = 0, s1 = 0, s2 = 0, t0 = 0, t1 = 0, u0 = 0, u1 = 0;
    for (int j = 0; j < 256; ++j) {
        float wr1 = Wr[1 * 65536 + j * 256 + n], wr3 = Wr[3 * 65536 + j * 256 + n];
        float wm1 = Wm[1 * 65536 + j * 256 + n], wm3 = Wm[3 * 65536 + j * 256 + n];
        float wm0 = Wm[0 * 65536 + j * 256 + n], wr0 = Wr[0 * 65536 + j * 256 + n];
        float wm2 = Wm[2 * 65536 + j * 256 + n], wr2 = Wr[2 * 65536 + j * 256 + n];
        float bc = bpc[j], b1 = bp1[j], b2 = bp2[j];
        s0 = fmaf(bc, 0.5f * (wr1 + wr3), s0);
        s1 = fmaf(b1, 0.5f * wm1, s1);
        s2 = fmaf(b2, 0.5f * wm3, s2);
        t0 = fmaf(bc, wm0, t0); t1 = fmaf(b1, wr0, t1);
        u0 = fmaf(bc, wm2, u0); u1 = fmaf(b2, wr2, u1);
    }
    bC[n]  = s0 + s1 + s2 + 0.5f * (bm[1 * 256 + n] + bm[3 * 256 + n]);
    bB1[n] = t0 + t1 + bm[0 * 256 + n];
    bB2[n] = u0 + u1 + bm[2 * 256 + n];
}

// layer-1 stacked per-graph weight [256][1792] transposed bf16 (x 1/3), + bias
__global__ void wpg_prep(const float* __restrict__ Wm, const float* __restrict__ Wr,
                         const float* __restrict__ bm, unsigned short* __restrict__ WPGt,
                         float* __restrict__ bPG) {
    int idx = blockIdx.x * 256 + threadIdx.x;
    const float third = 1.0f / 3.0f;
    if (idx < 256 * PGW) {
        int n = idx / PGW, k = idx - n * PGW;
        int blk = k >> 8, kk = k & 255;
        float v;
        switch (blk) {
            case 0:  v = 0.5f * Wm[1 * 65536 + kk * 256 + n]; break;
            case 1:  v = 0.5f * Wm[3 * 65536 + kk * 256 + n]; break;
            case 2:  v = 0.5f * (Wr[1 * 65536 + kk * 256 + n] + Wr[3 * 65536 + kk * 256 + n]); break;
            case 3:  v = Wm[0 * 65536 + kk * 256 + n]; break;
            case 4:  v = Wr[0 * 65536 + kk * 256 + n]; break;
            case 5:  v = Wm[2 * 65536 + kk * 256 + n]; break;
            default: v = Wr[2 * 65536 + kk * 256 + n]; break;
        }
        WPGt[idx] = f2bf(v * third);
    } else if (idx < 256 * PGW + 256) {
        int n = idx - 256 * PGW;
        bPG[n] = third * (0.5f * (bm[1 * 256 + n] + bm[3 * 256 + n]) + bm[0 * 256 + n] + bm[2 * 256 + n]);
    }
}

// ---------------- layer-0 GEMM: K=96, N=256, bias+relu, 3 fused instances --------------
struct G96 {
    const unsigned short* A;
    const unsigned short* Wt;
    const float* bias;
    unsigned short* C;
    int M;
};
__global__ void __launch_bounds__(256) gemm96(G96 g0, G96 g1, G96 g2) {
    G96 g = (blockIdx.y == 0) ? g0 : (blockIdx.y == 1) ? g1 : g2;
    const int m0 = blockIdx.x * 32;
    if (m0 >= g.M) return;
    const int tid = threadIdx.x;
    const int wid = tid >> 6, lane = tid & 63;
    const int llo = lane & 15, lhi = lane >> 4;
    const int cb = wid * 64;

    const unsigned short* pA[2];
#pragma unroll
    for (int rt = 0; rt < 2; ++rt)
        pA[rt] = g.A + (size_t)(m0 + rt * 16 + llo) * KA + lhi * 8;
    const unsigned short* pB[4];
#pragma unroll
    for (int ct = 0; ct < 4; ++ct)
        pB[ct] = g.Wt + (size_t)(cb + ct * 16 + llo) * KA + lhi * 8;

    f32x4 acc[2][4] = {};
    bf16x8 a0[2], a1[2], a2[2], b0[4], b1[4], b2[4];
#pragma unroll
    for (int t = 0; t < 2; ++t) {
        a0[t] = *reinterpret_cast<const bf16x8*>(pA[t]);
        a1[t] = *reinterpret_cast<const bf16x8*>(pA[t] + 32);
        a2[t] = *reinterpret_cast<const bf16x8*>(pA[t] + 64);
    }
#pragma unroll
    for (int t = 0; t < 4; ++t) {
        b0[t] = *reinterpret_cast<const bf16x8*>(pB[t]);
        b1[t] = *reinterpret_cast<const bf16x8*>(pB[t] + 32);
        b2[t] = *reinterpret_cast<const bf16x8*>(pB[t] + 64);
    }
#pragma unroll
    for (int rt = 0; rt < 2; ++rt)
#pragma unroll
        for (int ct = 0; ct < 4; ++ct) {
            acc[rt][ct] = __builtin_amdgcn_mfma_f32_16x16x32_bf16(b0[ct], a0[rt], acc[rt][ct], 0, 0, 0);
            acc[rt][ct] = __builtin_amdgcn_mfma_f32_16x16x32_bf16(b1[ct], a1[rt], acc[rt][ct], 0, 0, 0);
            acc[rt][ct] = __builtin_amdgcn_mfma_f32_16x16x32_bf16(b2[ct], a2[rt], acc[rt][ct], 0, 0, 0);
        }

#pragma unroll
    for (int rt = 0; rt < 2; ++rt) {
        const int row = m0 + rt * 16 + llo;
#pragma unroll
        for (int ct = 0; ct < 4; ++ct) {
            const int col0 = cb + ct * 16 + lhi * 4;
            float4 bv = *reinterpret_cast<const float4*>(g.bias + col0);
            float v0 = fmaxf(acc[rt][ct][0] + bv.x, 0.f);
            float v1 = fmaxf(acc[rt][ct][1] + bv.y, 0.f);
            float v2 = fmaxf(acc[rt][ct][2] + bv.z, 0.f);
            float v3 = fmaxf(acc[rt][ct][3] + bv.w, 0.f);
            ushort4 o;
            o.x = f2bf(v0); o.y = f2bf(v1); o.z = f2bf(v2); o.w = f2bf(v3);
            *reinterpret_cast<ushort4*>(g.C + (size_t)row * Hh + col0) = o;
        }
    }
}

// ---------------- per-graph aggregation (flat edge loop, 2-way ILP) --------------------
struct PGDesc {
    const unsigned short* feat;   // [*][256]
    const int* bound;             // 513 entries
    const int* rowptr;            // nullptr => plain mean over nodes
    const int* colsrc;
    const float* wedge;           // per-edge 1/deg in CSR order
    int ocol;
};
struct PGAll { PGDesc d[7]; };
__global__ void __launch_bounds__(256) pg_agg(PGAll all, unsigned short* __restrict__ PG) {
    PGDesc d = all.d[blockIdx.y];
    int g = blockIdx.x;
    int ns = d.bound[g], ne = d.bound[g + 1];
    int tid = threadIdx.x, wid = tid >> 6, lane = tid & 63;
    float a0 = 0.f, a1 = 0.f, a2 = 0.f, a3 = 0.f;
    float c0 = 0.f, c1 = 0.f, c2 = 0.f, c3 = 0.f;
    if (d.rowptr) {
        int es = d.rowptr[ns], ee = d.rowptr[ne];
        for (int i = es + wid * 2; i < ee; i += 8) {
            int s1 = d.colsrc[i];
            float w1 = d.wedge[i];
            ushort4 v1 = *reinterpret_cast<const ushort4*>(d.feat + (size_t)s1 * Hh + lane * 4);
            int i2 = i + 1;
            if (i2 < ee) {
                int s2 = d.colsrc[i2];
                float w2 = d.wedge[i2];
                ushort4 v2 = *reinterpret_cast<const ushort4*>(d.feat + (size_t)s2 * Hh + lane * 4);
                c0 = fmaf(bf2f(v2.x), w2, c0); c1 = fmaf(bf2f(v2.y), w2, c1);
                c2 = fmaf(bf2f(v2.z), w2, c2); c3 = fmaf(bf2f(v2.w), w2, c3);
            }
            a0 = fmaf(bf2f(v1.x), w1, a0); a1 = fmaf(bf2f(v1.y), w1, a1);
            a2 = fmaf(bf2f(v1.z), w1, a2); a3 = fmaf(bf2f(v1.w), w1, a3);
        }
    } else {
        for (int n = ns + wid; n < ne; n += 8) {
            ushort4 v1 = *reinterpret_cast<const ushort4*>(d.feat + (size_t)n * Hh + lane * 4);
            int n2 = n + 4;
            if (n2 < ne) {
                ushort4 v2 = *reinterpret_cast<const ushort4*>(d.feat + (size_t)n2 * Hh + lane * 4);
                c0 += bf2f(v2.x); c1 += bf2f(v2.y); c2 += bf2f(v2.z); c3 += bf2f(v2.w);
            }
            a0 += bf2f(v1.x); a1 += bf2f(v1.y); a2 += bf2f(v1.z); a3 += bf2f(v1.w);
        }
    }
    a0 += c0; a1 += c1; a2 += c2; a3 += c3;
    __shared__ float sh[4][256];
    sh[wid][lane * 4 + 0] = a0; sh[wid][lane * 4 + 1] = a1;
    sh[wid][lane * 4 + 2] = a2; sh[wid][lane * 4 + 3] = a3;
    __syncthreads();
    float r = sh[0][tid] + sh[1][tid] + sh[2][tid] + sh[3][tid];
    r *= 1.0f / (float)imax(ne - ns, 1);
    PG[(size_t)g * PGW + d.ocol + tid] = f2bf(r);
}

// ---------------- final: emb = PG @ WPGt + bPG (MFMA); out = emb @ Wg + bg -------------
__global__ void graph_bounds_all(const int* __restrict__ bc, const int* __restrict__ b1,
                                 const int* __restrict__ b2, int* __restrict__ bound) {
    int idx = blockIdx.x * 256 + threadIdx.x;
    if (idx >= 3 * (Bn + 1)) return;
    int t = idx / (Bn + 1); int b = idx - t * (Bn + 1);
    const int* batch = (t == 0) ? bc : (t == 1) ? b1 : b2;
    int n = (t == 0) ? NCn : (t == 1) ? N1n : N2n;
    int lo = 0, hi = n;
    while (lo < hi) { int mid = (lo + hi) >> 1; if (batch[mid] < b) lo = mid + 1; else hi = mid; }
    bound[idx] = lo;
}

__global__ void __launch_bounds__(256) gemm_emb(const unsigned short* __restrict__ PG,
                                                const unsigned short* __restrict__ WPGt,
                                                const float* __restrict__ bPG,
                                                float* __restrict__ emb) {
    constexpr int KSTEPS = PGW / 32;   // 56
    const int m0 = blockIdx.x * 32;
    const int tid = threadIdx.x;
    const int wid = tid >> 6, lane = tid & 63;
    const int llo = lane & 15, lhi = lane >> 4;
    const int cb = wid * 64;

    const unsigned short* pA[2];
#pragma unroll
    for (int rt = 0; rt < 2; ++rt)
        pA[rt] = PG + (size_t)(m0 + rt * 16 + llo) * PGW + lhi * 8;
    const unsigned short* pB[4];
#pragma unroll
    for (int ct = 0; ct < 4; ++ct)
        pB[ct] = WPGt + (size_t)(cb + ct * 16 + llo) * PGW + lhi * 8;

    f32x4 acc[2][4] = {};
    bf16x8 aX[2], bX[4], aY[2], bY[4];
    auto LD = [&](bf16x8 (&a)[2], bf16x8 (&b)[4], int ks) {
        if (ks < KSTEPS) {
            const int ko = ks * 32;
#pragma unroll
            for (int t = 0; t < 2; ++t) a[t] = *reinterpret_cast<const bf16x8*>(pA[t] + ko);
#pragma unroll
            for (int t = 0; t < 4; ++t) b[t] = *reinterpret_cast<const bf16x8*>(pB[t] + ko);
        }
    };
    auto FM = [&](bf16x8 (&a)[2], bf16x8 (&b)[4]) {
#pragma unroll
        for (int rt = 0; rt < 2; ++rt)
#pragma unroll
            for (int ct = 0; ct < 4; ++ct)
                acc[rt][ct] = __builtin_amdgcn_mfma_f32_16x16x32_bf16(b[ct], a[rt], acc[rt][ct], 0, 0, 0);
    };
    LD(aX, bX, 0);
    for (int ks = 0; ks < KSTEPS; ks += 2) {
        LD(aY, bY, ks + 1);
        FM(aX, bX);
        LD(aX, bX, ks + 2);
        FM(aY, bY);
    }

#pragma unroll
    for (int rt = 0; rt < 2; ++rt) {
        const int row = m0 + rt * 16 + llo;
#pragma unroll
        for (int ct = 0; ct < 4; ++ct) {
            const int col0 = cb + ct * 16 + lhi * 4;
            float4 bv = *reinterpret_cast<const float4*>(bPG + col0);
            float4 o;
            o.x = acc[rt][ct][0] + bv.x; o.y = acc[rt][ct][1] + bv.y;
            o.z = acc[rt][ct][2] + bv.z; o.w = acc[rt][ct][3] + bv.w;
            *reinterpret_cast<float4*>(emb + (size_t)row * Hh + col0) = o;
        }
    }
}

__global__ void __launch_bounds__(128) out_final(const float* __restrict__ emb,
                                                 const float* __restrict__ Wg,
                                                 const float* __restrict__ bg,
                                                 float* __restrict__ out) {
    __shared__ float es_[256];
    int g = blockIdx.x, o = threadIdx.x;
    es_[o] = emb[(size_t)g * Hh + o];
    es_[o + 128] = emb[(size_t)g * Hh + 128 + o];
    __syncthreads();
    float acc = bg[o];
#pragma unroll 8
    for (int k = 0; k < 256; ++k) acc = fmaf(es_[k], Wg[k * OUTn + o], acc);
    out[(size_t)g * OUTn + o] = acc;
}

// ---------------- host orchestration ----------------------------------------------------
extern "C" void kernel_launch(void* const* d_in, const int* in_sizes, int n_in,
                              void* d_out, int out_size, void* d_ws, size_t ws_size,
                              hipStream_t stream) {
    const float* x_central = (const float*)d_in[0];
    const float* x_cont    = (const float*)d_in[1];
    const float* x_categ   = (const float*)d_in[2];
    const int* ei_c2cont   = (const int*)d_in[3];
    const int* ei_cont2c   = (const int*)d_in[4];
    const int* ei_c2categ  = (const int*)d_in[5];
    const int* ei_categ2c  = (const int*)d_in[6];
    const int* batch_central = (const int*)d_in[7];
    const int* batch_cont    = (const int*)d_in[8];
    const int* batch_categ   = (const int*)d_in[9];
    const float* Wp_central = (const float*)d_in[11];
    const float* bp_central = (const float*)d_in[12];
    const float* Wp_cont    = (const float*)d_in[13];
    const float* bp_cont    = (const float*)d_in[14];
    const float* Wp_categ   = (const float*)d_in[15];
    const float* bp_categ   = (const float*)d_in[16];
    const float* W_msg  = (const float*)d_in[17];
    const float* b_msg  = (const float*)d_in[18];
    const float* W_root = (const float*)d_in[19];
    const float* Wg     = (const float*)d_in[20];
    const float* bg     = (const float*)d_in[21];
    float* out = (float*)d_out;

    char* base = (char*)d_ws;
    size_t off = 0;
    auto alloc = [&](size_t bytes) -> void* {
        off = (off + 255) & ~(size_t)255;
        void* p = base + off; off += bytes; return p;
    };

    unsigned short* A0  = (unsigned short*)alloc((size_t)NCn * KA * 2);
    unsigned short* A1  = (unsigned short*)alloc((size_t)N1n * KA * 2);
    unsigned short* A2  = (unsigned short*)alloc((size_t)N2n * KA * 2);
    unsigned short* hc1 = (unsigned short*)alloc((size_t)NCn * Hh * 2);
    unsigned short* h11 = (unsigned short*)alloc((size_t)N1n * Hh * 2);
    unsigned short* h21 = (unsigned short*)alloc((size_t)N2n * Hh * 2);
    unsigned short* PG  = (unsigned short*)alloc((size_t)Bn * PGW * 2);
    float* emb          = (float*)alloc((size_t)Bn * Hh * 4);

    unsigned short* Wt3  = (unsigned short*)alloc((size_t)3 * 256 * KA * 2);
    unsigned short* WPGt = (unsigned short*)alloc((size_t)256 * PGW * 2);
    float* bC  = (float*)alloc(256 * 4);
    float* bB1 = (float*)alloc(256 * 4);
    float* bB2 = (float*)alloc(256 * 4);
    float* bPG = (float*)alloc(256 * 4);

    const int nd[4] = { N1n, NCn, N2n, NCn };
    int* rp[4]; int* cs[4]; float* we[4];
    for (int r = 0; r < 4; ++r) {
        rp[r] = (int*)alloc((size_t)(nd[r] + 1) * 4);
        cs[r] = (int*)alloc((size_t)En * 4);
        we[r] = (float*)alloc((size_t)En * 4);
    }
    int* deg_fill = (int*)alloc((size_t)320000 * 4);
    int* partials = (int*)alloc(256 * 4);
    int* bounds   = (int*)alloc((size_t)3 * (Bn + 1) * 4);
    (void)ws_size; (void)in_sizes; (void)n_in; (void)out_size;

    const float* Wm0 = W_msg;
    const float* Wr0 = W_root;
    const float* Wm1 = W_msg  + (size_t)4 * 65536;
    const float* Wr1 = W_root + (size_t)4 * 65536;
    const float* bm0 = b_msg;
    const float* bm1 = b_msg + 4 * 256;

    // --- packing + weight prep ---
    pack_inputs<<<20000, 256, 0, stream>>>(x_central, x_cont, x_categ, A0, A1, A2);
    wfold<<<dim3(256, 3), 128, 0, stream>>>(Wm0, Wr0, Wp_central, Wp_cont, Wp_categ, Wt3);
    bias_fold<<<2, 128, 0, stream>>>(Wm0, Wr0, bm0, bp_central, bp_cont, bp_categ, bC, bB1, bB2);
    wpg_prep<<<1793, 256, 0, stream>>>(Wm1, Wr1, bm1, WPGt, bPG);
    graph_bounds_all<<<7, 256, 0, stream>>>(batch_central, batch_cont, batch_categ, bounds);

    // --- CSR build ---
    CPtr4 srcs = {{ ei_c2cont, ei_cont2c, ei_c2categ, ei_categ2c }};
    CPtr4 dsts = {{ ei_c2cont + En, ei_cont2c + En, ei_c2categ + En, ei_categ2c + En }};
    IPtr4 rps  = {{ rp[0], rp[1], rp[2], rp[3] }};
    CPtr4 rpc  = {{ rp[0], rp[1], rp[2], rp[3] }};
    IPtr4 css  = {{ cs[0], cs[1], cs[2], cs[3] }};
    FPtr4 wes  = {{ we[0], we[1], we[2], we[3] }};
    zero_i32<<<1250, 256, 0, stream>>>(deg_fill, 320000);
    deg_count_all<<<3125, 256, 0, stream>>>(dsts, deg_fill);
    scan_chunk_all<<<158, 1024, 0, stream>>>(deg_fill, rps, partials);
    scan_partials_all<<<4, 64, 0, stream>>>(partials);
    scan_add_all<<<158, 1024, 0, stream>>>(rps, partials);
    scatter_all<<<3125, 256, 0, stream>>>(srcs, dsts, rpc, deg_fill + 160000, css, wes);

    // --- layer-0 raw aggregations (into A panels) ---
    RawDesc r0 = { A1 + 64, rp[1], cs[1], A0, 2, NCn, 64 };
    RawDesc r1 = { A2 + 64, rp[3], cs[3], A0, 2, NCn, 80 };
    RawDesc r2 = { A0,      rp[0], cs[0], A1, 4, N1n, 0 };
    RawDesc r3 = { A0,      rp[2], cs[2], A2, 4, N2n, 0 };
    raw_agg<<<dim3(3750, 4), 256, 0, stream>>>(r0, r1, r2, r3);

    // --- layer-0 GEMMs (K=96, bias+relu) ---
    G96 gc = { A0, Wt3,                 bC,  hc1, NCn };
    G96 g1 = { A1, Wt3 + 1 * 256 * KA,  bB1, h11, N1n };
    G96 g2 = { A2, Wt3 + 2 * 256 * KA,  bB2, h21, N2n };
    gemm96<<<dim3(1875, 3), 256, 0, stream>>>(g1, g2, gc);

    // --- layer-1 collapsed to per-graph aggregation ---
    PGAll pa;
    pa.d[0] = { h11, bounds,                rp[1], cs[1], we[1], 0 };
    pa.d[1] = { h21, bounds,                rp[3], cs[3], we[3], 256 };
    pa.d[2] = { hc1, bounds,                nullptr, nullptr, nullptr, 512 };
    pa.d[3] = { hc1, bounds + (Bn + 1),     rp[0], cs[0], we[0], 768 };
    pa.d[4] = { h11, bounds + (Bn + 1),     nullptr, nullptr, nullptr, 1024 };
    pa.d[5] = { hc1, bounds + 2 * (Bn + 1), rp[2], cs[2], we[2], 1280 };
    pa.d[6] = { h21, bounds + 2 * (Bn + 1), nullptr, nullptr, nullptr, 1536 };
    pg_agg<<<dim3(Bn, 7), 256, 0, stream>>>(pa, PG);

    // --- final ---
    gemm_emb<<<Bn / 32, 256, 0, stream>>>(PG, WPGt, bPG, emb);
    out_final<<<Bn, 128, 0, stream>>>(emb, Wg, bg, out);
}